// Round 1
// baseline (41205.679 us; speedup 1.0000x reference)
//
#include <hip/hip_runtime.h>
#include <hip/hip_bf16.h>
#include <cstddef>

typedef __hip_bfloat16 bf16;

__device__ __forceinline__ float b2f(bf16 x) { return __bfloat162float(x); }
__device__ __forceinline__ float ldv(float x) { return x; }
__device__ __forceinline__ float ldv(bf16 x) { return __bfloat162float(x); }
__device__ __forceinline__ void stv(float* p, float v) { *p = v; }
__device__ __forceinline__ void stv(bf16* p, float v) { *p = __float2bfloat16(v); }

// ---------------------------------------------------------------------------
// K1: 3x3 conv pad1 + BN + ReLU on 16x16 planes. block 256 = 16x16 plane,
// co-tile 8. grid (CO/8, N). All-f32.
// ---------------------------------------------------------------------------
__global__ __launch_bounds__(256) void k_conv3x3_s(
    const float* __restrict__ in, const float* __restrict__ wgt,
    const float* __restrict__ sc, const float* __restrict__ bi,
    float* __restrict__ out, int CI, int CO)
{
    const int HW = 256;
    int co0 = blockIdx.x * 8;
    int n = blockIdx.y;
    int t = threadIdx.x;
    int y = t >> 4, x = t & 15;
    __shared__ float tile[4][324];  // 18x18 halo planes, 4 ci at a time
    float acc[8];
#pragma unroll
    for (int i = 0; i < 8; i++) acc[i] = 0.f;
    const float* inn = in + (size_t)n * CI * HW;
    for (int ci0 = 0; ci0 < CI; ci0 += 4) {
        __syncthreads();
        for (int i = t; i < 4 * 324; i += 256) {
            int cc = i / 324, r = i % 324;
            int yy = r / 18 - 1, xx = r % 18 - 1;
            float v = 0.f;
            if (yy >= 0 && yy < 16 && xx >= 0 && xx < 16)
                v = inn[(size_t)(ci0 + cc) * HW + yy * 16 + xx];
            tile[cc][r] = v;
        }
        __syncthreads();
#pragma unroll
        for (int cc = 0; cc < 4; cc++) {
            int ci = ci0 + cc;
            float v[9];
#pragma unroll
            for (int j = 0; j < 9; j++) {
                int dy = j / 3, dx = j % 3;
                v[j] = tile[cc][(y + dy) * 18 + (x + dx)];
            }
#pragma unroll
            for (int co = 0; co < 8; co++) {
                const float* w8 = wgt + ((size_t)(co0 + co) * CI + ci) * 9;
#pragma unroll
                for (int j = 0; j < 9; j++) acc[co] += w8[j] * v[j];
            }
        }
    }
#pragma unroll
    for (int co = 0; co < 8; co++) {
        float s = sc[co0 + co], b = bi[co0 + co];
        float r = fmaxf(acc[co] * s + b, 0.f);
        out[((size_t)n * CO + co0 + co) * HW + t] = r;
    }
}

// ---------------------------------------------------------------------------
// K2: bilinear resize, align_corners=True. thread per output element.
// ---------------------------------------------------------------------------
template <typename Tin, typename Tout>
__global__ void k_resize(const Tin* __restrict__ in, Tout* __restrict__ out,
                         int N, int C, int h, int w, int H, int W)
{
    size_t idx = (size_t)blockIdx.x * blockDim.x + threadIdx.x;
    size_t total = (size_t)N * C * H * W;
    if (idx >= total) return;
    int X = idx % W; size_t r = idx / W;
    int Y = r % H; r /= H;
    int c = r % C; int n = (int)(r / C);
    float sy = (H > 1) ? (float)(h - 1) / (float)(H - 1) : 0.f;
    float sx = (W > 1) ? (float)(w - 1) / (float)(W - 1) : 0.f;
    float ty = Y * sy, tx = X * sx;
    int y0 = (int)floorf(ty), x0 = (int)floorf(tx);
    int y1 = min(y0 + 1, h - 1), x1 = min(x0 + 1, w - 1);
    float wy = ty - y0, wx = tx - x0;
    const Tin* p = in + ((size_t)n * C + c) * h * w;
    float v00 = ldv(p[y0 * w + x0]), v01 = ldv(p[y0 * w + x1]);
    float v10 = ldv(p[y1 * w + x0]), v11 = ldv(p[y1 * w + x1]);
    float v = (v00 * (1.f - wy) + v10 * wy) * (1.f - wx)
            + (v01 * (1.f - wy) + v11 * wy) * wx;
    stv(&out[idx], v);
}

// ---------------------------------------------------------------------------
// K3: 1x1 conv + BN (+opt ReLU), f32 weights. block 256 pixels, co-tile 16.
// grid (ceil(HW/256), CO/16, N).
// ---------------------------------------------------------------------------
template <typename Tin>
__global__ void k_conv1x1(const Tin* __restrict__ in, const float* __restrict__ wgt,
                          const float* __restrict__ sc, const float* __restrict__ bi,
                          float* __restrict__ out, int CI, int CO, int HW, int relu)
{
    int p = blockIdx.x * 256 + threadIdx.x;
    int co0 = blockIdx.y * 16;
    int n = blockIdx.z;
    if (p >= HW) return;
    const Tin* ip = in + (size_t)n * CI * HW + p;
    float acc[16];
#pragma unroll
    for (int i = 0; i < 16; i++) acc[i] = 0.f;
    for (int ci = 0; ci < CI; ci++) {
        float v = ldv(ip[(size_t)ci * HW]);
#pragma unroll
        for (int co = 0; co < 16; co++)
            acc[co] += wgt[(size_t)(co0 + co) * CI + ci] * v;
    }
#pragma unroll
    for (int co = 0; co < 16; co++) {
        float r = acc[co] * sc[co0 + co] + bi[co0 + co];
        if (relu) r = fmaxf(r, 0.f);
        out[((size_t)n * CO + co0 + co) * HW + p] = r;
    }
}

// ---------------------------------------------------------------------------
// K3b: fused bilinear-2x-upsample + 1x1 conv + BN. Input SHxSH f32, output
// (2*SH)x(2*SH) f32. (1x1 conv commutes with per-channel bilinear resize.)
// grid (ceil(HW/256), CO/16, N).
// ---------------------------------------------------------------------------
template <int SH>
__global__ void k_conv1x1_up(const float* __restrict__ in, const float* __restrict__ wgt,
                             const float* __restrict__ sc, const float* __restrict__ bi,
                             float* __restrict__ out, int CI, int CO)
{
    const int OH = 2 * SH, HW = OH * OH, sHW = SH * SH;
    int p = blockIdx.x * 256 + threadIdx.x;
    int co0 = blockIdx.y * 16;
    int n = blockIdx.z;
    if (p >= HW) return;
    int Y = p / OH, X = p % OH;
    float s = (float)(SH - 1) / (float)(OH - 1);
    float ty = Y * s, tx = X * s;
    int y0 = (int)floorf(ty), x0 = (int)floorf(tx);
    int y1 = min(y0 + 1, SH - 1), x1 = min(x0 + 1, SH - 1);
    float wy = ty - y0, wx = tx - x0;
    float w00 = (1.f - wy) * (1.f - wx), w01 = (1.f - wy) * wx;
    float w10 = wy * (1.f - wx),         w11 = wy * wx;
    int o00 = y0 * SH + x0, o01 = y0 * SH + x1;
    int o10 = y1 * SH + x0, o11 = y1 * SH + x1;
    const float* ip = in + (size_t)n * CI * sHW;
    float acc[16];
#pragma unroll
    for (int i = 0; i < 16; i++) acc[i] = 0.f;
    for (int ci = 0; ci < CI; ci++) {
        const float* pp = ip + (size_t)ci * sHW;
        float v = w00 * pp[o00] + w01 * pp[o01] + w10 * pp[o10] + w11 * pp[o11];
#pragma unroll
        for (int co = 0; co < 16; co++)
            acc[co] += wgt[(size_t)(co0 + co) * CI + ci] * v;
    }
#pragma unroll
    for (int co = 0; co < 16; co++)
        out[((size_t)n * CO + co0 + co) * HW + p] =
            acc[co] * sc[co0 + co] + bi[co0 + co];
}

// ---------------------------------------------------------------------------
// K4: attention logits + softmax. q,k: [N,KD,H,W] f32 -> att [N,H,W,9].
// unfold: kernel 3, dilation 2, pad 2 -> offsets {-2,0,2}. OOB taps keep
// logit 0 (zero-padded k) and still participate in softmax (matches ref).
// ---------------------------------------------------------------------------
__global__ void k_attn(const float* __restrict__ q, const float* __restrict__ k,
                       float* __restrict__ att, int KD, int H, int W)
{
    int p = blockIdx.x * 256 + threadIdx.x;
    int n = blockIdx.y;
    if (p >= H * W) return;
    int y = p / W, x = p % W;
    float dot[9];
    bool val[9];
    int off[9];
#pragma unroll
    for (int j = 0; j < 9; j++) {
        dot[j] = 0.f;
        int dy = (j / 3) * 2 - 2, dx = (j % 3) * 2 - 2;
        int yy = y + dy, xx = x + dx;
        val[j] = (yy >= 0 && yy < H && xx >= 0 && xx < W);
        off[j] = yy * W + xx;
    }
    const float* qp = q + (size_t)n * KD * H * W + p;
    const float* kp = k + (size_t)n * KD * H * W;
    for (int c = 0; c < KD; c++) {
        float qa = qp[(size_t)c * H * W];
        const float* kc = kp + (size_t)c * H * W;
#pragma unroll
        for (int j = 0; j < 9; j++)
            if (val[j]) dot[j] += qa * kc[off[j]];
    }
    float m = dot[0];
#pragma unroll
    for (int j = 1; j < 9; j++) m = fmaxf(m, dot[j]);
    float s = 0.f, e[9];
#pragma unroll
    for (int j = 0; j < 9; j++) { e[j] = expf(dot[j] - m); s += e[j]; }
    float inv = 1.f / s;
    float* ap = att + ((size_t)n * H * W + p) * 9;
#pragma unroll
    for (int j = 0; j < 9; j++) ap[j] = e[j] * inv;
}

// ---------------------------------------------------------------------------
// K5: apply attention: out[n,c,y,x] = sum_j att[n,y,x,j] * v[n,c,y+dy,x+dx]
// (zero pad). grid (HW/256, C, N).
// ---------------------------------------------------------------------------
template <typename Tv, typename Tout>
__global__ void k_apply(const float* __restrict__ att, const Tv* __restrict__ v,
                        Tout* __restrict__ out, int C, int H, int W)
{
    int p = blockIdx.x * 256 + threadIdx.x;
    int c = blockIdx.y, n = blockIdx.z;
    if (p >= H * W) return;
    int y = p / W, x = p % W;
    const float* ap = att + ((size_t)n * H * W + p) * 9;
    const Tv* vp = v + ((size_t)n * C + c) * H * W;
    float s = 0.f;
#pragma unroll
    for (int j = 0; j < 9; j++) {
        int dy = (j / 3) * 2 - 2, dx = (j % 3) * 2 - 2;
        int yy = y + dy, xx = x + dx;
        if (yy >= 0 && yy < H && xx >= 0 && xx < W) s += ap[j] * ldv(vp[yy * W + xx]);
    }
    stv(&out[((size_t)n * C + c) * H * W + p], s);
}

// ---------------------------------------------------------------------------
// K6: adaptive avg pool (torch bins) from bf16 out3 [N,512,64,64].
// One wave (64 thr) per (bin, c, n). grid (s*s, C, N).
// ---------------------------------------------------------------------------
__global__ void k_apool(const bf16* __restrict__ in, float* __restrict__ out,
                        int C, int s)
{
    int bin = blockIdx.x, c = blockIdx.y, n = blockIdx.z;
    int bi = bin / s, bj = bin % s;
    int h0 = (bi * 64) / s, h1 = ((bi + 1) * 64 + s - 1) / s;
    int w0 = (bj * 64) / s, w1 = ((bj + 1) * 64 + s - 1) / s;
    int nh = h1 - h0, nw = w1 - w0, tot = nh * nw;
    const bf16* p = in + ((size_t)n * C + c) * 4096;
    float sum = 0.f;
    for (int i = threadIdx.x; i < tot; i += 64) {
        int yy = h0 + i / nw, xx = w0 + i % nw;
        sum += b2f(p[yy * 64 + xx]);
    }
#pragma unroll
    for (int o = 32; o > 0; o >>= 1) sum += __shfl_down(sum, o);
    if (threadIdx.x == 0) out[((size_t)n * C + c) * s * s + bin] = sum / tot;
}

// ---------------------------------------------------------------------------
// K7: precompute M[n][seg][j][g][co] = sum_c w[co, 512+seg*512+c, j] *
// fpool_seg[n, c, g]. Exact factorization of "3x3 conv over bilinear-
// upsampled pooled planes": the 2048 virtual channels are linear in the 50
// pooled grid values with channel-independent bilinear coefficients, so
// conv contribution = sum_{j,g} beta(pixel, j, g) * M[co,j,g].
// grid (2 co-tiles, 50 flattened (seg,g)), block 256 = co. n looped inside
// (4x weight reuse). M per-n stride = 230400 floats; seg offsets
// {0, 4608, 23040, 64512} (9*s*s*512 each).
// ---------------------------------------------------------------------------
__global__ __launch_bounds__(256) void k_precm(
    const float* __restrict__ fpool, const float* __restrict__ wgt,
    float* __restrict__ M)
{
    int gflat = blockIdx.y;
    int seg, g, s;
    if (gflat < 1)       { seg = 0; g = gflat;      s = 1; }
    else if (gflat < 5)  { seg = 1; g = gflat - 1;  s = 2; }
    else if (gflat < 14) { seg = 2; g = gflat - 5;  s = 3; }
    else                 { seg = 3; g = gflat - 14; s = 6; }
    const int pofs[4] = {0, 2048, 10240, 28672};
    const int moff[4] = {0, 4608, 23040, 64512};
    int t = threadIdx.x;
    int co = blockIdx.x * 256 + t;
    int cbase = 512 + seg * 512;
    __shared__ float fsm[4][512];
    for (int i = t; i < 4 * 512; i += 256) {
        int nn = i >> 9, c = i & 511;
        fsm[nn][c] = fpool[pofs[seg] + ((size_t)(nn * 512 + c)) * s * s + g];
    }
    __syncthreads();
    float acc[4][9];
#pragma unroll
    for (int nn = 0; nn < 4; nn++)
#pragma unroll
        for (int j = 0; j < 9; j++) acc[nn][j] = 0.f;
    const float* wp = wgt + ((size_t)co * 2560 + cbase) * 9;
    for (int c = 0; c < 512; c++) {
        float w9[9];
#pragma unroll
        for (int j = 0; j < 9; j++) w9[j] = wp[c * 9 + j];
#pragma unroll
        for (int nn = 0; nn < 4; nn++) {
            float f = fsm[nn][c];
#pragma unroll
            for (int j = 0; j < 9; j++) acc[nn][j] += f * w9[j];
        }
    }
    int G = s * s;
#pragma unroll
    for (int nn = 0; nn < 4; nn++)
#pragma unroll
        for (int j = 0; j < 9; j++)
            M[(size_t)nn * 230400 + moff[seg] + ((size_t)j * G + g) * 512 + co]
                = acc[nn][j];
}

// ---------------------------------------------------------------------------
// K8: big 3x3 conv + BN + ReLU over 64x64, fp32 register-blocked. Only the
// 512 REAL channels (out3, bf16) go through the direct conv; the 2048
// virtual channels (upsampled pooled features) are applied exactly via the
// factorized M tensor in the epilogue (<=144 FMA per pixel per co vs 18432
// MACs direct -- 80% of the original work removed, same math).
// block 256; tile 32 rows x 64 cols; thread: 8 rows x 8 co accumulators.
// grid (2 rowtiles, 64 cotiles, N). bf16 output (internal).
// ---------------------------------------------------------------------------
#define CCAT 2560
__global__ __launch_bounds__(256) void k_pcw(
    const bf16* __restrict__ out3, const float* __restrict__ wgt,
    const float* __restrict__ sc, const float* __restrict__ bi,
    const float* __restrict__ M, bf16* __restrict__ out)
{
    __shared__ float tile[2][34 * 66];
    __shared__ float wsm[8 * 2 * 9];
    int t = threadIdx.x;
    int col = t & 63, rowg = t >> 6;
    int rbase = blockIdx.x * 32;
    int co0 = blockIdx.y * 8;
    int n = blockIdx.z;
    float acc[8][8];  // [co][row]
#pragma unroll
    for (int a = 0; a < 8; a++)
#pragma unroll
        for (int b = 0; b < 8; b++) acc[a][b] = 0.f;
    const bf16* inn = out3 + (size_t)n * 512 * 4096;
    for (int ci0 = 0; ci0 < 512; ci0 += 2) {
        __syncthreads();
        for (int i = t; i < 2 * 2244; i += 256) {
            int cl = i / 2244, r = i % 2244;
            int yy = r / 66 - 1 + rbase, xx = r % 66 - 1;
            float v = 0.f;
            if (yy >= 0 && yy < 64 && xx >= 0 && xx < 64)
                v = b2f(inn[(size_t)(ci0 + cl) * 4096 + yy * 64 + xx]);
            tile[cl][r] = v;
        }
        if (t < 144) {
            int co = t / 18, r = t % 18, cl = r / 9, j = r % 9;
            wsm[t] = wgt[((size_t)(co0 + co) * CCAT + ci0 + cl) * 9 + j];
        }
        __syncthreads();
#pragma unroll
        for (int cl = 0; cl < 2; cl++) {
#pragma unroll
            for (int j = 0; j < 9; j++) {
                int dy = j / 3, dx = j % 3;
                float v[8];
#pragma unroll
                for (int rr = 0; rr < 8; rr++)
                    v[rr] = tile[cl][(rowg * 8 + rr + dy) * 66 + col + dx];
#pragma unroll
                for (int co = 0; co < 8; co++) {
                    float wv = wsm[(co * 2 + cl) * 9 + j];
#pragma unroll
                    for (int rr = 0; rr < 8; rr++) acc[co][rr] += wv * v[rr];
                }
            }
        }
    }
    // --- correction: virtual channels [512,2560) via factorized M ---
    const float* Mn = M + (size_t)n * 230400;
    {
        const int sarr[3] = {2, 3, 6};
        const int moff[3] = {4608, 23040, 64512};
#pragma unroll
        for (int rr = 0; rr < 8; rr++) {
            int y = rbase + rowg * 8 + rr;
            int x = col;
            // seg 0 (s=1): constant plane per channel -> coeff 1 per valid tap
#pragma unroll
            for (int j = 0; j < 9; j++) {
                int yy = y + j / 3 - 1, xx = x + j % 3 - 1;
                if (yy < 0 || yy > 63 || xx < 0 || xx > 63) continue;
                const float* mp = Mn + (size_t)j * 512 + co0;
#pragma unroll
                for (int co = 0; co < 8; co++) acc[co][rr] += mp[co];
            }
#pragma unroll
            for (int sg = 0; sg < 3; sg++) {
                int s = sarr[sg];
                const float* Ms = Mn + moff[sg];
                float scl = (float)(s - 1) * (1.f / 63.f);
                int G = s * s;
#pragma unroll
                for (int j = 0; j < 9; j++) {
                    int yy = y + j / 3 - 1, xx = x + j % 3 - 1;
                    if (yy < 0 || yy > 63 || xx < 0 || xx > 63) continue;
                    float ty = yy * scl, tx = xx * scl;
                    int y0 = (int)ty, x0 = (int)tx;
                    int y1 = min(y0 + 1, s - 1), x1 = min(x0 + 1, s - 1);
                    float wy = ty - (float)y0, wx = tx - (float)x0;
                    float cw00 = (1.f - wy) * (1.f - wx), cw01 = (1.f - wy) * wx;
                    float cw10 = wy * (1.f - wx),          cw11 = wy * wx;
                    const float* m00 = Ms + ((size_t)j * G + y0 * s + x0) * 512 + co0;
                    const float* m01 = Ms + ((size_t)j * G + y0 * s + x1) * 512 + co0;
                    const float* m10 = Ms + ((size_t)j * G + y1 * s + x0) * 512 + co0;
                    const float* m11 = Ms + ((size_t)j * G + y1 * s + x1) * 512 + co0;
#pragma unroll
                    for (int co = 0; co < 8; co++)
                        acc[co][rr] += cw00 * m00[co] + cw01 * m01[co]
                                     + cw10 * m10[co] + cw11 * m11[co];
                }
            }
        }
    }
#pragma unroll
    for (int co = 0; co < 8; co++) {
        float s = sc[co0 + co], b = bi[co0 + co];
#pragma unroll
        for (int rr = 0; rr < 8; rr++) {
            int y = rbase + rowg * 8 + rr;
            float r = fmaxf(acc[co][rr] * s + b, 0.f);
            out[(((size_t)n * 512 + co0 + co) * 64 + y) * 64 + col] = __float2bfloat16(r);
        }
    }
}

// ---------------------------------------------------------------------------
// K9: final 1x1 conv 512->19 + bias, f32 out. grid (16, N), block 256.
// ---------------------------------------------------------------------------
__global__ void k_final(const bf16* __restrict__ in, const float* __restrict__ wgt,
                        const float* __restrict__ bi, float* __restrict__ out)
{
    int p = blockIdx.x * 256 + threadIdx.x;
    int n = blockIdx.y;
    float acc[19];
#pragma unroll
    for (int j = 0; j < 19; j++) acc[j] = bi[j];
    const bf16* ip = in + (size_t)n * 512 * 4096 + p;
    for (int ci = 0; ci < 512; ci++) {
        float v = b2f(ip[(size_t)ci * 4096]);
#pragma unroll
        for (int j = 0; j < 19; j++) acc[j] += wgt[j * 512 + ci] * v;
    }
#pragma unroll
    for (int j = 0; j < 19; j++)
        out[((size_t)n * 19 + j) * 4096 + p] = acc[j];
}

// ---------------------------------------------------------------------------
extern "C" void kernel_launch(void* const* d_in, const int* in_sizes, int n_in,
                              void* d_out, int out_size, void* d_ws, size_t ws_size,
                              hipStream_t stream)
{
    // ALL inputs are float32 (per the reference's setup_inputs dtypes).
    const float* c2   = (const float*)d_in[1];
    const float* c3   = (const float*)d_in[2];
    const float* c4   = (const float*)d_in[3];
    const float* w5   = (const float*)d_in[4];
    const float* s5   = (const float*)d_in[5];
    const float* b5   = (const float*)d_in[6];
    const float* r4w  = (const float*)d_in[7];
    const float* r4s  = (const float*)d_in[8];
    const float* r4b  = (const float*)d_in[9];
    const float* r4w2 = (const float*)d_in[10];
    const float* r4s2 = (const float*)d_in[11];
    const float* r4b2 = (const float*)d_in[12];
    const float* r3w  = (const float*)d_in[13];
    const float* r3s  = (const float*)d_in[14];
    const float* r3b  = (const float*)d_in[15];
    const float* r3w2 = (const float*)d_in[16];
    const float* r3s2 = (const float*)d_in[17];
    const float* r3b2 = (const float*)d_in[18];
    const float* pw[4] = { (const float*)d_in[19], (const float*)d_in[22],
                           (const float*)d_in[25], (const float*)d_in[28] };
    const float* ps[4] = { (const float*)d_in[20], (const float*)d_in[23],
                           (const float*)d_in[26], (const float*)d_in[29] };
    const float* pb[4] = { (const float*)d_in[21], (const float*)d_in[24],
                           (const float*)d_in[27], (const float*)d_in[30] };
    const float* pcw  = (const float*)d_in[31];
    const float* pcs  = (const float*)d_in[32];
    const float* pcb  = (const float*)d_in[33];
    const float* w6   = (const float*)d_in[34];
    const float* b6   = (const float*)d_in[35];
    float* outp = (float*)d_out;

    // --- workspace arena, peak 58,490,880 B (55.8 MiB). Live ranges:
    // R0 [0,15728640): out5[T1..T4], q4/k4[T2..T3], att4[T3..T5],
    //                  out5r[T4..T5]; then q3/k3[T6..T7], att3[T7..T9];
    //                  then Mbuf (3,686,400 B) [T10.5..T11]
    // R1: out4 f32 [T5..T8]
    // R2: out4r bf16 [T8..T9], then out_pc bf16 [T11..T12] (disjoint in time)
    // R3: out3 bf16 [T9..T11]
    // R4: pooled/fpool f32 [T10..T11]
    char* ws = (char*)d_ws;
    float* out5   = (float*)(ws + 0);          // 2,097,152
    float* q4     = (float*)(ws + 2097152);    // 2,097,152
    float* k4     = (float*)(ws + 4194304);    // 2,097,152
    float* att4   = (float*)(ws + 6291456);    //   147,456
    float* out5r  = (float*)(ws + 6438912);    // 8,388,608 (ends 14,827,520)
    float* q3     = (float*)(ws + 0);          // 4,194,304 (R0 reuse)
    float* k3     = (float*)(ws + 4194304);    // 4,194,304
    float* att3   = (float*)(ws + 8388608);    //   589,824
    float* Mbuf   = (float*)(ws + 0);          // 3,686,400 (R0 reuse, T10.5+)
    float* out4   = (float*)(ws + 15728640);   // 8,388,608
    bf16*  out4r  = (bf16*)(ws + 24117248);    // 16,777,216
    bf16*  out_pc = (bf16*)(ws + 24117248);    // alias, disjoint in time
    bf16*  out3   = (bf16*)(ws + 40894464);    // 16,777,216
    float* pooled = (float*)(ws + 57671680);   //   409,600
    float* fpool  = (float*)(ws + 58081280);   //   409,600 (ends 58,490,880)

    // T1: out5 = relu(bn(conv3x3(c4, w5)))           [4,512,16,16]
    k_conv3x3_s<<<dim3(64, 4), 256, 0, stream>>>(c4, w5, s5, b5, out5, 2048, 512);
    // T2: q4 = bn(conv1x1(c3)); k4 = bn(conv1x1(resize(c4,32))) fused
    k_conv1x1<float><<<dim3(4, 8, 4), 256, 0, stream>>>(c3, r4w, r4s, r4b, q4, 1024, 128, 1024, 0);
    k_conv1x1_up<16><<<dim3(4, 8, 4), 256, 0, stream>>>(c4, r4w2, r4s2, r4b2, k4, 2048, 128);
    // T3: att4 = softmax(q4 . unfold(k4))            [4,32,32,9]
    k_attn<<<dim3(4, 4), 256, 0, stream>>>(q4, k4, att4, 128, 32, 32);
    // T4: out5r = resize(out5, 32x32)
    k_resize<float, float><<<8192, 256, 0, stream>>>(out5, out5r, 4, 512, 16, 16, 32, 32);
    // T5: out4 = att4 * unfold(out5r)                [4,512,32,32]
    k_apply<float, float><<<dim3(4, 512, 4), 256, 0, stream>>>(att4, out5r, out4, 512, 32, 32);
    // T6: q3 = bn(conv1x1(c2)); k3 = bn(conv1x1(resize(c3,64))) fused
    k_conv1x1<float><<<dim3(16, 4, 4), 256, 0, stream>>>(c2, r3w, r3s, r3b, q3, 512, 64, 4096, 0);
    k_conv1x1_up<32><<<dim3(16, 4, 4), 256, 0, stream>>>(c3, r3w2, r3s2, r3b2, k3, 1024, 64);
    // T7: att3                                        [4,64,64,9]
    k_attn<<<dim3(16, 4), 256, 0, stream>>>(q3, k3, att3, 64, 64, 64);
    // T8: out4r = resize(out4, 64x64) -> bf16
    k_resize<float, bf16><<<32768, 256, 0, stream>>>(out4, out4r, 4, 512, 32, 32, 64, 64);
    // T9: out3 = att3 * unfold(out4r) -> bf16        [4,512,64,64]
    k_apply<bf16, bf16><<<dim3(16, 512, 4), 256, 0, stream>>>(att3, out4r, out3, 512, 64, 64);
    // T10: PSP pools + 1x1 conv+bn+relu -> fpool (tiny)
    const int scales[4] = {1, 2, 3, 6};
    const int poff[4] = {0, 2048, 10240, 28672};  // f32 elem offsets
    for (int i = 0; i < 4; i++) {
        int s = scales[i];
        k_apool<<<dim3(s * s, 512, 4), 64, 0, stream>>>(out3, pooled + poff[i], 512, s);
        k_conv1x1<float><<<dim3(1, 32, 4), 256, 0, stream>>>(pooled + poff[i], pw[i], ps[i], pb[i],
                                                             fpool + poff[i], 512, 512, s * s, 1);
    }
    // T10.5: M[n,seg,j,g,co] = sum_c pcw[co,512+seg*512+c,j] * fpool[n,c,g]
    k_precm<<<dim3(2, 50), 256, 0, stream>>>(fpool, pcw, Mbuf);
    // T11: out_pc = relu(bn(conv3x3(real 512 ch) + M-correction)) [4,512,64,64] bf16
    k_pcw<<<dim3(2, 64, 4), 256, 0, stream>>>(out3, pcw, pcs, pcb, Mbuf, out_pc);
    // T12: out = conv1x1(out_pc, w6) + b6 -> f32     [4,19,64,64]
    k_final<<<dim3(16, 4), 256, 0, stream>>>(out_pc, w6, b6, outp);
}

// Round 2
// 8547.301 us; speedup vs baseline: 4.8209x; 4.8209x over previous
//
#include <hip/hip_runtime.h>
#include <hip/hip_bf16.h>
#include <cstddef>

typedef __hip_bfloat16 bf16;

__device__ __forceinline__ float b2f(bf16 x) { return __bfloat162float(x); }
__device__ __forceinline__ float ldv(float x) { return x; }
__device__ __forceinline__ float ldv(bf16 x) { return __bfloat162float(x); }
__device__ __forceinline__ void stv(float* p, float v) { *p = v; }
__device__ __forceinline__ void stv(bf16* p, float v) { *p = __float2bfloat16(v); }

// ---------------------------------------------------------------------------
// K1: 3x3 conv pad1 + BN + ReLU on 16x16 planes. block 256 = 16x16 plane,
// co-tile 8. grid (CO/8, N). All-f32.
// ---------------------------------------------------------------------------
__global__ __launch_bounds__(256) void k_conv3x3_s(
    const float* __restrict__ in, const float* __restrict__ wgt,
    const float* __restrict__ sc, const float* __restrict__ bi,
    float* __restrict__ out, int CI, int CO)
{
    const int HW = 256;
    int co0 = blockIdx.x * 8;
    int n = blockIdx.y;
    int t = threadIdx.x;
    int y = t >> 4, x = t & 15;
    __shared__ float tile[4][324];  // 18x18 halo planes, 4 ci at a time
    float acc[8];
#pragma unroll
    for (int i = 0; i < 8; i++) acc[i] = 0.f;
    const float* inn = in + (size_t)n * CI * HW;
    for (int ci0 = 0; ci0 < CI; ci0 += 4) {
        __syncthreads();
        for (int i = t; i < 4 * 324; i += 256) {
            int cc = i / 324, r = i % 324;
            int yy = r / 18 - 1, xx = r % 18 - 1;
            float v = 0.f;
            if (yy >= 0 && yy < 16 && xx >= 0 && xx < 16)
                v = inn[(size_t)(ci0 + cc) * HW + yy * 16 + xx];
            tile[cc][r] = v;
        }
        __syncthreads();
#pragma unroll
        for (int cc = 0; cc < 4; cc++) {
            int ci = ci0 + cc;
            float v[9];
#pragma unroll
            for (int j = 0; j < 9; j++) {
                int dy = j / 3, dx = j % 3;
                v[j] = tile[cc][(y + dy) * 18 + (x + dx)];
            }
#pragma unroll
            for (int co = 0; co < 8; co++) {
                const float* w8 = wgt + ((size_t)(co0 + co) * CI + ci) * 9;
#pragma unroll
                for (int j = 0; j < 9; j++) acc[co] += w8[j] * v[j];
            }
        }
    }
#pragma unroll
    for (int co = 0; co < 8; co++) {
        float s = sc[co0 + co], b = bi[co0 + co];
        float r = fmaxf(acc[co] * s + b, 0.f);
        out[((size_t)n * CO + co0 + co) * HW + t] = r;
    }
}

// ---------------------------------------------------------------------------
// K2: bilinear resize, align_corners=True. thread per output element.
// ---------------------------------------------------------------------------
template <typename Tin, typename Tout>
__global__ void k_resize(const Tin* __restrict__ in, Tout* __restrict__ out,
                         int N, int C, int h, int w, int H, int W)
{
    size_t idx = (size_t)blockIdx.x * blockDim.x + threadIdx.x;
    size_t total = (size_t)N * C * H * W;
    if (idx >= total) return;
    int X = idx % W; size_t r = idx / W;
    int Y = r % H; r /= H;
    int c = r % C; int n = (int)(r / C);
    float sy = (H > 1) ? (float)(h - 1) / (float)(H - 1) : 0.f;
    float sx = (W > 1) ? (float)(w - 1) / (float)(W - 1) : 0.f;
    float ty = Y * sy, tx = X * sx;
    int y0 = (int)floorf(ty), x0 = (int)floorf(tx);
    int y1 = min(y0 + 1, h - 1), x1 = min(x0 + 1, w - 1);
    float wy = ty - y0, wx = tx - x0;
    const Tin* p = in + ((size_t)n * C + c) * h * w;
    float v00 = ldv(p[y0 * w + x0]), v01 = ldv(p[y0 * w + x1]);
    float v10 = ldv(p[y1 * w + x0]), v11 = ldv(p[y1 * w + x1]);
    float v = (v00 * (1.f - wy) + v10 * wy) * (1.f - wx)
            + (v01 * (1.f - wy) + v11 * wy) * wx;
    stv(&out[idx], v);
}

// ---------------------------------------------------------------------------
// K3: 1x1 conv + BN (+opt ReLU), f32 weights. block 256 pixels, co-tile 16.
// grid (ceil(HW/256), CO/16, N).
// ---------------------------------------------------------------------------
template <typename Tin>
__global__ void k_conv1x1(const Tin* __restrict__ in, const float* __restrict__ wgt,
                          const float* __restrict__ sc, const float* __restrict__ bi,
                          float* __restrict__ out, int CI, int CO, int HW, int relu)
{
    int p = blockIdx.x * 256 + threadIdx.x;
    int co0 = blockIdx.y * 16;
    int n = blockIdx.z;
    if (p >= HW) return;
    const Tin* ip = in + (size_t)n * CI * HW + p;
    float acc[16];
#pragma unroll
    for (int i = 0; i < 16; i++) acc[i] = 0.f;
    for (int ci = 0; ci < CI; ci++) {
        float v = ldv(ip[(size_t)ci * HW]);
#pragma unroll
        for (int co = 0; co < 16; co++)
            acc[co] += wgt[(size_t)(co0 + co) * CI + ci] * v;
    }
#pragma unroll
    for (int co = 0; co < 16; co++) {
        float r = acc[co] * sc[co0 + co] + bi[co0 + co];
        if (relu) r = fmaxf(r, 0.f);
        out[((size_t)n * CO + co0 + co) * HW + p] = r;
    }
}

// ---------------------------------------------------------------------------
// K3b: fused bilinear-2x-upsample + 1x1 conv + BN. Input SHxSH f32, output
// (2*SH)x(2*SH) f32. (1x1 conv commutes with per-channel bilinear resize.)
// grid (ceil(HW/256), CO/16, N).
// ---------------------------------------------------------------------------
template <int SH>
__global__ void k_conv1x1_up(const float* __restrict__ in, const float* __restrict__ wgt,
                             const float* __restrict__ sc, const float* __restrict__ bi,
                             float* __restrict__ out, int CI, int CO)
{
    const int OH = 2 * SH, HW = OH * OH, sHW = SH * SH;
    int p = blockIdx.x * 256 + threadIdx.x;
    int co0 = blockIdx.y * 16;
    int n = blockIdx.z;
    if (p >= HW) return;
    int Y = p / OH, X = p % OH;
    float s = (float)(SH - 1) / (float)(OH - 1);
    float ty = Y * s, tx = X * s;
    int y0 = (int)floorf(ty), x0 = (int)floorf(tx);
    int y1 = min(y0 + 1, SH - 1), x1 = min(x0 + 1, SH - 1);
    float wy = ty - y0, wx = tx - x0;
    float w00 = (1.f - wy) * (1.f - wx), w01 = (1.f - wy) * wx;
    float w10 = wy * (1.f - wx),         w11 = wy * wx;
    int o00 = y0 * SH + x0, o01 = y0 * SH + x1;
    int o10 = y1 * SH + x0, o11 = y1 * SH + x1;
    const float* ip = in + (size_t)n * CI * sHW;
    float acc[16];
#pragma unroll
    for (int i = 0; i < 16; i++) acc[i] = 0.f;
    for (int ci = 0; ci < CI; ci++) {
        const float* pp = ip + (size_t)ci * sHW;
        float v = w00 * pp[o00] + w01 * pp[o01] + w10 * pp[o10] + w11 * pp[o11];
#pragma unroll
        for (int co = 0; co < 16; co++)
            acc[co] += wgt[(size_t)(co0 + co) * CI + ci] * v;
    }
#pragma unroll
    for (int co = 0; co < 16; co++)
        out[((size_t)n * CO + co0 + co) * HW + p] =
            acc[co] * sc[co0 + co] + bi[co0 + co];
}

// ---------------------------------------------------------------------------
// K4: attention logits + softmax. q,k: [N,KD,H,W] f32 -> att [N,H,W,9].
// unfold: kernel 3, dilation 2, pad 2 -> offsets {-2,0,2}. OOB taps keep
// logit 0 (zero-padded k) and still participate in softmax (matches ref).
// ---------------------------------------------------------------------------
__global__ void k_attn(const float* __restrict__ q, const float* __restrict__ k,
                       float* __restrict__ att, int KD, int H, int W)
{
    int p = blockIdx.x * 256 + threadIdx.x;
    int n = blockIdx.y;
    if (p >= H * W) return;
    int y = p / W, x = p % W;
    float dot[9];
    bool val[9];
    int off[9];
#pragma unroll
    for (int j = 0; j < 9; j++) {
        dot[j] = 0.f;
        int dy = (j / 3) * 2 - 2, dx = (j % 3) * 2 - 2;
        int yy = y + dy, xx = x + dx;
        val[j] = (yy >= 0 && yy < H && xx >= 0 && xx < W);
        off[j] = yy * W + xx;
    }
    const float* qp = q + (size_t)n * KD * H * W + p;
    const float* kp = k + (size_t)n * KD * H * W;
    for (int c = 0; c < KD; c++) {
        float qa = qp[(size_t)c * H * W];
        const float* kc = kp + (size_t)c * H * W;
#pragma unroll
        for (int j = 0; j < 9; j++)
            if (val[j]) dot[j] += qa * kc[off[j]];
    }
    float m = dot[0];
#pragma unroll
    for (int j = 1; j < 9; j++) m = fmaxf(m, dot[j]);
    float s = 0.f, e[9];
#pragma unroll
    for (int j = 0; j < 9; j++) { e[j] = expf(dot[j] - m); s += e[j]; }
    float inv = 1.f / s;
    float* ap = att + ((size_t)n * H * W + p) * 9;
#pragma unroll
    for (int j = 0; j < 9; j++) ap[j] = e[j] * inv;
}

// ---------------------------------------------------------------------------
// K5: apply attention: out[n,c,y,x] = sum_j att[n,y,x,j] * v[n,c,y+dy,x+dx]
// (zero pad). grid (HW/256, C, N).
// ---------------------------------------------------------------------------
template <typename Tv, typename Tout>
__global__ void k_apply(const float* __restrict__ att, const Tv* __restrict__ v,
                        Tout* __restrict__ out, int C, int H, int W)
{
    int p = blockIdx.x * 256 + threadIdx.x;
    int c = blockIdx.y, n = blockIdx.z;
    if (p >= H * W) return;
    int y = p / W, x = p % W;
    const float* ap = att + ((size_t)n * H * W + p) * 9;
    const Tv* vp = v + ((size_t)n * C + c) * H * W;
    float s = 0.f;
#pragma unroll
    for (int j = 0; j < 9; j++) {
        int dy = (j / 3) * 2 - 2, dx = (j % 3) * 2 - 2;
        int yy = y + dy, xx = x + dx;
        if (yy >= 0 && yy < H && xx >= 0 && xx < W) s += ap[j] * ldv(vp[yy * W + xx]);
    }
    stv(&out[((size_t)n * C + c) * H * W + p], s);
}

// ---------------------------------------------------------------------------
// K6: adaptive avg pool (torch bins) from bf16 out3 [N,512,64,64].
// One wave (64 thr) per (bin, c, n). grid (s*s, C, N).
// ---------------------------------------------------------------------------
__global__ void k_apool(const bf16* __restrict__ in, float* __restrict__ out,
                        int C, int s)
{
    int bin = blockIdx.x, c = blockIdx.y, n = blockIdx.z;
    int bi = bin / s, bj = bin % s;
    int h0 = (bi * 64) / s, h1 = ((bi + 1) * 64 + s - 1) / s;
    int w0 = (bj * 64) / s, w1 = ((bj + 1) * 64 + s - 1) / s;
    int nh = h1 - h0, nw = w1 - w0, tot = nh * nw;
    const bf16* p = in + ((size_t)n * C + c) * 4096;
    float sum = 0.f;
    for (int i = threadIdx.x; i < tot; i += 64) {
        int yy = h0 + i / nw, xx = w0 + i % nw;
        sum += b2f(p[yy * 64 + xx]);
    }
#pragma unroll
    for (int o = 32; o > 0; o >>= 1) sum += __shfl_down(sum, o);
    if (threadIdx.x == 0) out[((size_t)n * C + c) * s * s + bin] = sum / tot;
}

// ---------------------------------------------------------------------------
// K7: precompute M[n][seg][j][g][co] = sum_c w[co, 512+seg*512+c, j] *
// fpool_seg[n, c, g]. Exact factorization of "3x3 conv over bilinear-
// upsampled pooled planes". (Math verified in round 1 — passed.)
// grid (2 co-tiles, 50 flattened (seg,g)), block 256 = co.
// ---------------------------------------------------------------------------
__global__ __launch_bounds__(256) void k_precm(
    const float* __restrict__ fpool, const float* __restrict__ wgt,
    float* __restrict__ M)
{
    int gflat = blockIdx.y;
    int seg, g, s;
    if (gflat < 1)       { seg = 0; g = gflat;      s = 1; }
    else if (gflat < 5)  { seg = 1; g = gflat - 1;  s = 2; }
    else if (gflat < 14) { seg = 2; g = gflat - 5;  s = 3; }
    else                 { seg = 3; g = gflat - 14; s = 6; }
    const int pofs[4] = {0, 2048, 10240, 28672};
    const int moff[4] = {0, 4608, 23040, 64512};
    int t = threadIdx.x;
    int co = blockIdx.x * 256 + t;
    int cbase = 512 + seg * 512;
    __shared__ float fsm[4][512];
    for (int i = t; i < 4 * 512; i += 256) {
        int nn = i >> 9, c = i & 511;
        fsm[nn][c] = fpool[pofs[seg] + ((size_t)(nn * 512 + c)) * s * s + g];
    }
    __syncthreads();
    float acc[4][9];
#pragma unroll
    for (int nn = 0; nn < 4; nn++)
#pragma unroll
        for (int j = 0; j < 9; j++) acc[nn][j] = 0.f;
    const float* wp = wgt + ((size_t)co * 2560 + cbase) * 9;
    for (int c = 0; c < 512; c++) {
        float w9[9];
#pragma unroll
        for (int j = 0; j < 9; j++) w9[j] = wp[c * 9 + j];
#pragma unroll
        for (int nn = 0; nn < 4; nn++) {
            float f = fsm[nn][c];
#pragma unroll
            for (int j = 0; j < 9; j++) acc[nn][j] += f * w9[j];
        }
    }
    int G = s * s;
#pragma unroll
    for (int nn = 0; nn < 4; nn++)
#pragma unroll
        for (int j = 0; j < 9; j++)
            M[(size_t)nn * 230400 + moff[seg] + ((size_t)j * G + g) * 512 + co]
                = acc[nn][j];
}

// ---------------------------------------------------------------------------
// K7b: materialize the correction field corr[n,co,y,x] (bf16) from M.
// corr = sum over valid taps j of { M_seg0[j,0,co] + bilinear(M_seg[j,:,co]) }.
// Separate kernel so k_pcw's accumulators stay in registers (round-1 fusion
// spilled acc to scratch: VGPR 124->76, 147 GB scratch writes).
// block 256: x = t&63, 16 co per thread. grid (64 y, 8 co-tiles, N).
// ---------------------------------------------------------------------------
__global__ __launch_bounds__(256) void k_corr(
    const float* __restrict__ M, bf16* __restrict__ corr)
{
    int y = blockIdx.x;
    int n = blockIdx.z;
    int t = threadIdx.x;
    int x = t & 63;
    int co0 = blockIdx.y * 64 + (t >> 6) * 16;
    const float* Mn = M + (size_t)n * 230400;
    const int sarr[3] = {2, 3, 6};
    const int moff[3] = {4608, 23040, 64512};
    float acc[16];
#pragma unroll
    for (int i = 0; i < 16; i++) acc[i] = 0.f;
#pragma unroll
    for (int j = 0; j < 9; j++) {
        int yy = y + j / 3 - 1, xx = x + j % 3 - 1;
        if (yy < 0 || yy > 63 || xx < 0 || xx > 63) continue;
        // seg 0 (s=1): constant plane -> coefficient 1
        const float* mp = Mn + (size_t)j * 512 + co0;
#pragma unroll
        for (int i = 0; i < 16; i++) acc[i] += mp[i];
#pragma unroll
        for (int sg = 0; sg < 3; sg++) {
            int s = sarr[sg];
            int G = s * s;
            float scl = (float)(s - 1) * (1.f / 63.f);
            float ty = yy * scl, tx = xx * scl;
            int y0 = (int)ty, x0 = (int)tx;
            int y1 = min(y0 + 1, s - 1), x1 = min(x0 + 1, s - 1);
            float wy = ty - (float)y0, wx = tx - (float)x0;
            float cw00 = (1.f - wy) * (1.f - wx), cw01 = (1.f - wy) * wx;
            float cw10 = wy * (1.f - wx),          cw11 = wy * wx;
            const float* Ms = Mn + moff[sg];
            const float* m00 = Ms + ((size_t)j * G + y0 * s + x0) * 512 + co0;
            const float* m01 = Ms + ((size_t)j * G + y0 * s + x1) * 512 + co0;
            const float* m10 = Ms + ((size_t)j * G + y1 * s + x0) * 512 + co0;
            const float* m11 = Ms + ((size_t)j * G + y1 * s + x1) * 512 + co0;
#pragma unroll
            for (int i = 0; i < 16; i++)
                acc[i] += cw00 * m00[i] + cw01 * m01[i]
                        + cw10 * m10[i] + cw11 * m11[i];
        }
    }
#pragma unroll
    for (int i = 0; i < 16; i++)
        corr[(((size_t)n * 512 + co0 + i) * 64 + y) * 64 + x] = __float2bfloat16(acc[i]);
}

// ---------------------------------------------------------------------------
// K8: 3x3 conv + BN + ReLU over 64x64, fp32 register-blocked. Only the 512
// REAL channels (out3, bf16) go through the direct conv; the 2048 virtual
// channels arrive as one precomputed corr plane added in the epilogue
// (one coalesced bf16 load per output — register profile = baseline).
// block 256; tile 32 rows x 64 cols; thread: 8 rows x 8 co accumulators.
// grid (2 rowtiles, 64 cotiles, N). bf16 output (internal).
// ---------------------------------------------------------------------------
#define CCAT 2560
__global__ __launch_bounds__(256) void k_pcw(
    const bf16* __restrict__ out3, const float* __restrict__ wgt,
    const float* __restrict__ sc, const float* __restrict__ bi,
    const bf16* __restrict__ corr, bf16* __restrict__ out)
{
    __shared__ float tile[2][34 * 66];
    __shared__ float wsm[8 * 2 * 9];
    int t = threadIdx.x;
    int col = t & 63, rowg = t >> 6;
    int rbase = blockIdx.x * 32;
    int co0 = blockIdx.y * 8;
    int n = blockIdx.z;
    float acc[8][8];  // [co][row]
#pragma unroll
    for (int a = 0; a < 8; a++)
#pragma unroll
        for (int b = 0; b < 8; b++) acc[a][b] = 0.f;
    const bf16* inn = out3 + (size_t)n * 512 * 4096;
    for (int ci0 = 0; ci0 < 512; ci0 += 2) {
        __syncthreads();
        for (int i = t; i < 2 * 2244; i += 256) {
            int cl = i / 2244, r = i % 2244;
            int yy = r / 66 - 1 + rbase, xx = r % 66 - 1;
            float v = 0.f;
            if (yy >= 0 && yy < 64 && xx >= 0 && xx < 64)
                v = b2f(inn[(size_t)(ci0 + cl) * 4096 + yy * 64 + xx]);
            tile[cl][r] = v;
        }
        if (t < 144) {
            int co = t / 18, r = t % 18, cl = r / 9, j = r % 9;
            wsm[t] = wgt[((size_t)(co0 + co) * CCAT + ci0 + cl) * 9 + j];
        }
        __syncthreads();
#pragma unroll
        for (int cl = 0; cl < 2; cl++) {
#pragma unroll
            for (int j = 0; j < 9; j++) {
                int dy = j / 3, dx = j % 3;
                float v[8];
#pragma unroll
                for (int rr = 0; rr < 8; rr++)
                    v[rr] = tile[cl][(rowg * 8 + rr + dy) * 66 + col + dx];
#pragma unroll
                for (int co = 0; co < 8; co++) {
                    float wv = wsm[(co * 2 + cl) * 9 + j];
#pragma unroll
                    for (int rr = 0; rr < 8; rr++) acc[co][rr] += wv * v[rr];
                }
            }
        }
    }
    // virtual-channel contribution: one coalesced bf16 load per output
    const bf16* cp = corr + ((size_t)n * 512 + co0) * 4096;
#pragma unroll
    for (int co = 0; co < 8; co++) {
#pragma unroll
        for (int rr = 0; rr < 8; rr++) {
            int y = rbase + rowg * 8 + rr;
            acc[co][rr] += b2f(cp[(size_t)co * 4096 + y * 64 + col]);
        }
    }
#pragma unroll
    for (int co = 0; co < 8; co++) {
        float s = sc[co0 + co], b = bi[co0 + co];
#pragma unroll
        for (int rr = 0; rr < 8; rr++) {
            int y = rbase + rowg * 8 + rr;
            float r = fmaxf(acc[co][rr] * s + b, 0.f);
            out[(((size_t)n * 512 + co0 + co) * 64 + y) * 64 + col] = __float2bfloat16(r);
        }
    }
}

// ---------------------------------------------------------------------------
// K9: final 1x1 conv 512->19 + bias, f32 out. grid (16, N), block 256.
// ---------------------------------------------------------------------------
__global__ void k_final(const bf16* __restrict__ in, const float* __restrict__ wgt,
                        const float* __restrict__ bi, float* __restrict__ out)
{
    int p = blockIdx.x * 256 + threadIdx.x;
    int n = blockIdx.y;
    float acc[19];
#pragma unroll
    for (int j = 0; j < 19; j++) acc[j] = bi[j];
    const bf16* ip = in + (size_t)n * 512 * 4096 + p;
    for (int ci = 0; ci < 512; ci++) {
        float v = b2f(ip[(size_t)ci * 4096]);
#pragma unroll
        for (int j = 0; j < 19; j++) acc[j] += wgt[j * 512 + ci] * v;
    }
#pragma unroll
    for (int j = 0; j < 19; j++)
        out[((size_t)n * 19 + j) * 4096 + p] = acc[j];
}

// ---------------------------------------------------------------------------
extern "C" void kernel_launch(void* const* d_in, const int* in_sizes, int n_in,
                              void* d_out, int out_size, void* d_ws, size_t ws_size,
                              hipStream_t stream)
{
    // ALL inputs are float32 (per the reference's setup_inputs dtypes).
    const float* c2   = (const float*)d_in[1];
    const float* c3   = (const float*)d_in[2];
    const float* c4   = (const float*)d_in[3];
    const float* w5   = (const float*)d_in[4];
    const float* s5   = (const float*)d_in[5];
    const float* b5   = (const float*)d_in[6];
    const float* r4w  = (const float*)d_in[7];
    const float* r4s  = (const float*)d_in[8];
    const float* r4b  = (const float*)d_in[9];
    const float* r4w2 = (const float*)d_in[10];
    const float* r4s2 = (const float*)d_in[11];
    const float* r4b2 = (const float*)d_in[12];
    const float* r3w  = (const float*)d_in[13];
    const float* r3s  = (const float*)d_in[14];
    const float* r3b  = (const float*)d_in[15];
    const float* r3w2 = (const float*)d_in[16];
    const float* r3s2 = (const float*)d_in[17];
    const float* r3b2 = (const float*)d_in[18];
    const float* pw[4] = { (const float*)d_in[19], (const float*)d_in[22],
                           (const float*)d_in[25], (const float*)d_in[28] };
    const float* ps[4] = { (const float*)d_in[20], (const float*)d_in[23],
                           (const float*)d_in[26], (const float*)d_in[29] };
    const float* pb[4] = { (const float*)d_in[21], (const float*)d_in[24],
                           (const float*)d_in[27], (const float*)d_in[30] };
    const float* pcw  = (const float*)d_in[31];
    const float* pcs  = (const float*)d_in[32];
    const float* pcb  = (const float*)d_in[33];
    const float* w6   = (const float*)d_in[34];
    const float* b6   = (const float*)d_in[35];
    float* outp = (float*)d_out;

    // --- workspace arena, peak 58,490,880 B (55.8 MiB). Live ranges:
    // R0 [0,15728640): out5[T1..T4], q4/k4[T2..T3], att4[T3..T5],
    //                  out5r[T4..T5]; then q3/k3[T6..T7], att3[T7..T9];
    //                  then Mbuf [T10.5..T11) at 0 and out_pc [T11..T12)
    //                  at 3686400 (q3/k3/att3/out4 all dead by then)
    // R1: out4 f32 [T5..T8]; tail of out_pc overlaps (out4 dead) ✓
    // R2: out4r bf16 [T8..T9], then corr bf16 [T10.6..T11] (disjoint)
    // R3: out3 bf16 [T9..T11]
    // R4: pooled/fpool f32 [T10..T10.5]
    char* ws = (char*)d_ws;
    float* out5   = (float*)(ws + 0);          // 2,097,152
    float* q4     = (float*)(ws + 2097152);    // 2,097,152
    float* k4     = (float*)(ws + 4194304);    // 2,097,152
    float* att4   = (float*)(ws + 6291456);    //   147,456
    float* out5r  = (float*)(ws + 6438912);    // 8,388,608 (ends 14,827,520)
    float* q3     = (float*)(ws + 0);          // 4,194,304 (R0 reuse)
    float* k3     = (float*)(ws + 4194304);    // 4,194,304
    float* att3   = (float*)(ws + 8388608);    //   589,824
    float* Mbuf   = (float*)(ws + 0);          // 3,686,400 (R0 reuse, T10.5+)
    bf16*  out_pc = (bf16*)(ws + 3686400);     // 16,777,216 (ends 20,463,616)
    float* out4   = (float*)(ws + 15728640);   // 8,388,608
    bf16*  out4r  = (bf16*)(ws + 24117248);    // 16,777,216
    bf16*  corr   = (bf16*)(ws + 24117248);    // alias, disjoint in time
    bf16*  out3   = (bf16*)(ws + 40894464);    // 16,777,216
    float* pooled = (float*)(ws + 57671680);   //   409,600
    float* fpool  = (float*)(ws + 58081280);   //   409,600 (ends 58,490,880)

    // T1: out5 = relu(bn(conv3x3(c4, w5)))           [4,512,16,16]
    k_conv3x3_s<<<dim3(64, 4), 256, 0, stream>>>(c4, w5, s5, b5, out5, 2048, 512);
    // T2: q4 = bn(conv1x1(c3)); k4 = bn(conv1x1(resize(c4,32))) fused
    k_conv1x1<float><<<dim3(4, 8, 4), 256, 0, stream>>>(c3, r4w, r4s, r4b, q4, 1024, 128, 1024, 0);
    k_conv1x1_up<16><<<dim3(4, 8, 4), 256, 0, stream>>>(c4, r4w2, r4s2, r4b2, k4, 2048, 128);
    // T3: att4 = softmax(q4 . unfold(k4))            [4,32,32,9]
    k_attn<<<dim3(4, 4), 256, 0, stream>>>(q4, k4, att4, 128, 32, 32);
    // T4: out5r = resize(out5, 32x32)
    k_resize<float, float><<<8192, 256, 0, stream>>>(out5, out5r, 4, 512, 16, 16, 32, 32);
    // T5: out4 = att4 * unfold(out5r)                [4,512,32,32]
    k_apply<float, float><<<dim3(4, 512, 4), 256, 0, stream>>>(att4, out5r, out4, 512, 32, 32);
    // T6: q3 = bn(conv1x1(c2)); k3 = bn(conv1x1(resize(c3,64))) fused
    k_conv1x1<float><<<dim3(16, 4, 4), 256, 0, stream>>>(c2, r3w, r3s, r3b, q3, 512, 64, 4096, 0);
    k_conv1x1_up<32><<<dim3(16, 4, 4), 256, 0, stream>>>(c3, r3w2, r3s2, r3b2, k3, 1024, 64);
    // T7: att3                                        [4,64,64,9]
    k_attn<<<dim3(16, 4), 256, 0, stream>>>(q3, k3, att3, 64, 64, 64);
    // T8: out4r = resize(out4, 64x64) -> bf16
    k_resize<float, bf16><<<32768, 256, 0, stream>>>(out4, out4r, 4, 512, 32, 32, 64, 64);
    // T9: out3 = att3 * unfold(out4r) -> bf16        [4,512,64,64]
    k_apply<bf16, bf16><<<dim3(16, 512, 4), 256, 0, stream>>>(att3, out4r, out3, 512, 64, 64);
    // T10: PSP pools + 1x1 conv+bn+relu -> fpool (tiny)
    const int scales[4] = {1, 2, 3, 6};
    const int poff[4] = {0, 2048, 10240, 28672};  // f32 elem offsets
    for (int i = 0; i < 4; i++) {
        int s = scales[i];
        k_apool<<<dim3(s * s, 512, 4), 64, 0, stream>>>(out3, pooled + poff[i], 512, s);
        k_conv1x1<float><<<dim3(1, 32, 4), 256, 0, stream>>>(pooled + poff[i], pw[i], ps[i], pb[i],
                                                             fpool + poff[i], 512, 512, s * s, 1);
    }
    // T10.5: M[n,seg,j,g,co] = sum_c pcw[co,512+seg*512+c,j] * fpool[n,c,g]
    k_precm<<<dim3(2, 50), 256, 0, stream>>>(fpool, pcw, Mbuf);
    // T10.6: corr[n,co,y,x] = per-pixel bilinear combination of M (bf16)
    k_corr<<<dim3(64, 8, 4), 256, 0, stream>>>(Mbuf, corr);
    // T11: out_pc = relu(bn(conv3x3(real 512 ch) + corr)) [4,512,64,64] bf16
    k_pcw<<<dim3(2, 64, 4), 256, 0, stream>>>(out3, pcw, pcs, pcb, corr, out_pc);
    // T12: out = conv1x1(out_pc, w6) + b6 -> f32     [4,19,64,64]
    k_final<<<dim3(16, 4), 256, 0, stream>>>(out_pc, w6, b6, outp);
}

// Round 4
// 6104.110 us; speedup vs baseline: 6.7505x; 1.4003x over previous
//
#include <hip/hip_runtime.h>
#include <hip/hip_bf16.h>
#include <cstddef>

typedef __hip_bfloat16 bf16;

__device__ __forceinline__ float b2f(bf16 x) { return __bfloat162float(x); }
__device__ __forceinline__ float ldv(float x) { return x; }
__device__ __forceinline__ float ldv(bf16 x) { return __bfloat162float(x); }
__device__ __forceinline__ void stv(float* p, float v) { *p = v; }
__device__ __forceinline__ void stv(bf16* p, float v) { *p = __float2bfloat16(v); }

// ---------------------------------------------------------------------------
// K1: 3x3 conv pad1 on 16x16 planes, 2048ci -> 512co, K-SPLIT 16.
// Each block: 8 co x 128 ci x all 4 n x 256 px -> f32 partials.
// block 256 (=16x16 px); per thread: acc[8 co][4 n].
// LDS tile stride 24 (rows = 16 mod 32 pairwise -> 2-way banks = free).
// Weights staged [cc][j][co] so 8-co row = 2 x float4 broadcast reads.
// NOTE: weight tile is 288 entries > 256 threads -> MUST use strided loop
// (round-3 bug: `if (t < 288)` left 32 entries uninitialized).
// grid (64 co-tiles, 16 k). BN+ReLU moved to k_red16.
// ---------------------------------------------------------------------------
__global__ __launch_bounds__(256, 2) void k_conv3x3_ks(
    const float* __restrict__ in,   // [4,2048,16,16]
    const float* __restrict__ wgt,  // [512,2048,3,3]
    float* __restrict__ pbuf)       // [16,4,512,256]
{
    __shared__ float tile[16 * 432];   // [nn*4+cc][18 rows * 24 stride]
    __shared__ float wsm[4 * 9 * 8];   // [cc][j][co]
    int t = threadIdx.x;
    int x = t & 15, y = t >> 4;
    int co0 = blockIdx.x * 8;
    int k = blockIdx.y;
    int ci_beg = k * 128;
    float acc[8][4];  // [co][nn]
#pragma unroll
    for (int a = 0; a < 8; a++)
#pragma unroll
        for (int b = 0; b < 4; b++) acc[a][b] = 0.f;
    for (int ci0 = ci_beg; ci0 < ci_beg + 128; ci0 += 4) {
        __syncthreads();
        for (int i = t; i < 16 * 324; i += 256) {
            int pl = i / 324, r = i % 324;
            int nn = pl >> 2, cc = pl & 3;
            int yy = r / 18 - 1, xx = r % 18 - 1;
            float v = 0.f;
            if (yy >= 0 && yy < 16 && xx >= 0 && xx < 16)
                v = in[(((size_t)nn * 2048 + ci0 + cc) << 8) + (yy << 4) + xx];
            tile[pl * 432 + (r / 18) * 24 + (r % 18)] = v;
        }
        for (int i = t; i < 288; i += 256) {  // strided: 288 > blockDim!
            int cc = i / 72;
            int r = i % 72, j = r >> 3, co = r & 7;
            wsm[i] = wgt[((size_t)(co0 + co) * 2048 + ci0 + cc) * 9 + j];
        }
        __syncthreads();
#pragma unroll
        for (int cc = 0; cc < 4; cc++) {
#pragma unroll
            for (int j = 0; j < 9; j++) {
                int dy = j / 3, dx = j % 3;
                float vv[4];
#pragma unroll
                for (int nn = 0; nn < 4; nn++)
                    vv[nn] = tile[(nn * 4 + cc) * 432 + (y + dy) * 24 + (x + dx)];
                const float4* wp = reinterpret_cast<const float4*>(&wsm[(cc * 9 + j) * 8]);
                float4 wa = wp[0], wb = wp[1];
                float w8[8] = {wa.x, wa.y, wa.z, wa.w, wb.x, wb.y, wb.z, wb.w};
#pragma unroll
                for (int co = 0; co < 8; co++)
#pragma unroll
                    for (int nn = 0; nn < 4; nn++)
                        acc[co][nn] += w8[co] * vv[nn];
            }
        }
    }
#pragma unroll
    for (int co = 0; co < 8; co++)
#pragma unroll
        for (int nn = 0; nn < 4; nn++)
            pbuf[(((size_t)k * 4 + nn) * 512 + co0 + co) * 256 + t] = acc[co][nn];
}

// ---------------------------------------------------------------------------
// K1b: reduce 16 partials + BN + ReLU -> out5 [4,512,16,16].
// ---------------------------------------------------------------------------
__global__ void k_red16(const float* __restrict__ pbuf,
                        const float* __restrict__ sc, const float* __restrict__ bi,
                        float* __restrict__ out)
{
    int idx = blockIdx.x * 256 + threadIdx.x;  // 4*512*256 total
    int p = idx & 255;
    int co = (idx >> 8) & 511;
    int n = idx >> 17;
    float s = 0.f;
#pragma unroll
    for (int k = 0; k < 16; k++)
        s += pbuf[(((size_t)k * 4 + n) * 512 + co) * 256 + p];
    out[idx] = fmaxf(s * sc[co] + bi[co], 0.f);
}

// ---------------------------------------------------------------------------
// K2: bilinear resize, align_corners=True. thread per output element.
// ---------------------------------------------------------------------------
template <typename Tin, typename Tout>
__global__ void k_resize(const Tin* __restrict__ in, Tout* __restrict__ out,
                         int N, int C, int h, int w, int H, int W)
{
    size_t idx = (size_t)blockIdx.x * blockDim.x + threadIdx.x;
    size_t total = (size_t)N * C * H * W;
    if (idx >= total) return;
    int X = idx % W; size_t r = idx / W;
    int Y = r % H; r /= H;
    int c = r % C; int n = (int)(r / C);
    float sy = (H > 1) ? (float)(h - 1) / (float)(H - 1) : 0.f;
    float sx = (W > 1) ? (float)(w - 1) / (float)(W - 1) : 0.f;
    float ty = Y * sy, tx = X * sx;
    int y0 = (int)floorf(ty), x0 = (int)floorf(tx);
    int y1 = min(y0 + 1, h - 1), x1 = min(x0 + 1, w - 1);
    float wy = ty - y0, wx = tx - x0;
    const Tin* p = in + ((size_t)n * C + c) * h * w;
    float v00 = ldv(p[y0 * w + x0]), v01 = ldv(p[y0 * w + x1]);
    float v10 = ldv(p[y1 * w + x0]), v11 = ldv(p[y1 * w + x1]);
    float v = (v00 * (1.f - wy) + v10 * wy) * (1.f - wx)
            + (v01 * (1.f - wy) + v11 * wy) * wx;
    stv(&out[idx], v);
}

// ---------------------------------------------------------------------------
// K3: 1x1 conv + BN (+opt ReLU), f32 weights. block 256 pixels, co-tile 16.
// grid (ceil(HW/256), CO/16, N).
// ---------------------------------------------------------------------------
template <typename Tin>
__global__ void k_conv1x1(const Tin* __restrict__ in, const float* __restrict__ wgt,
                          const float* __restrict__ sc, const float* __restrict__ bi,
                          float* __restrict__ out, int CI, int CO, int HW, int relu)
{
    int p = blockIdx.x * 256 + threadIdx.x;
    int co0 = blockIdx.y * 16;
    int n = blockIdx.z;
    if (p >= HW) return;
    const Tin* ip = in + (size_t)n * CI * HW + p;
    float acc[16];
#pragma unroll
    for (int i = 0; i < 16; i++) acc[i] = 0.f;
    for (int ci = 0; ci < CI; ci++) {
        float v = ldv(ip[(size_t)ci * HW]);
#pragma unroll
        for (int co = 0; co < 16; co++)
            acc[co] += wgt[(size_t)(co0 + co) * CI + ci] * v;
    }
#pragma unroll
    for (int co = 0; co < 16; co++) {
        float r = acc[co] * sc[co0 + co] + bi[co0 + co];
        if (relu) r = fmaxf(r, 0.f);
        out[((size_t)n * CO + co0 + co) * HW + p] = r;
    }
}

// ---------------------------------------------------------------------------
// K3b: fused bilinear-2x-upsample + 1x1 conv + BN. Input SHxSH f32, output
// (2*SH)x(2*SH) f32. (1x1 conv commutes with per-channel bilinear resize.)
// grid (ceil(HW/256), CO/16, N).
// ---------------------------------------------------------------------------
template <int SH>
__global__ void k_conv1x1_up(const float* __restrict__ in, const float* __restrict__ wgt,
                             const float* __restrict__ sc, const float* __restrict__ bi,
                             float* __restrict__ out, int CI, int CO)
{
    const int OH = 2 * SH, HW = OH * OH, sHW = SH * SH;
    int p = blockIdx.x * 256 + threadIdx.x;
    int co0 = blockIdx.y * 16;
    int n = blockIdx.z;
    if (p >= HW) return;
    int Y = p / OH, X = p % OH;
    float s = (float)(SH - 1) / (float)(OH - 1);
    float ty = Y * s, tx = X * s;
    int y0 = (int)floorf(ty), x0 = (int)floorf(tx);
    int y1 = min(y0 + 1, SH - 1), x1 = min(x0 + 1, SH - 1);
    float wy = ty - y0, wx = tx - x0;
    float w00 = (1.f - wy) * (1.f - wx), w01 = (1.f - wy) * wx;
    float w10 = wy * (1.f - wx),         w11 = wy * wx;
    int o00 = y0 * SH + x0, o01 = y0 * SH + x1;
    int o10 = y1 * SH + x0, o11 = y1 * SH + x1;
    const float* ip = in + (size_t)n * CI * sHW;
    float acc[16];
#pragma unroll
    for (int i = 0; i < 16; i++) acc[i] = 0.f;
    for (int ci = 0; ci < CI; ci++) {
        const float* pp = ip + (size_t)ci * sHW;
        float v = w00 * pp[o00] + w01 * pp[o01] + w10 * pp[o10] + w11 * pp[o11];
#pragma unroll
        for (int co = 0; co < 16; co++)
            acc[co] += wgt[(size_t)(co0 + co) * CI + ci] * v;
    }
#pragma unroll
    for (int co = 0; co < 16; co++)
        out[((size_t)n * CO + co0 + co) * HW + p] =
            acc[co] * sc[co0 + co] + bi[co0 + co];
}

// ---------------------------------------------------------------------------
// K4: attention logits + softmax. q,k: [N,KD,H,W] f32 -> att [N,H,W,9].
// unfold: kernel 3, dilation 2, pad 2 -> offsets {-2,0,2}. OOB taps keep
// logit 0 (zero-padded k) and still participate in softmax (matches ref).
// ---------------------------------------------------------------------------
__global__ void k_attn(const float* __restrict__ q, const float* __restrict__ k,
                       float* __restrict__ att, int KD, int H, int W)
{
    int p = blockIdx.x * 256 + threadIdx.x;
    int n = blockIdx.y;
    if (p >= H * W) return;
    int y = p / W, x = p % W;
    float dot[9];
    bool val[9];
    int off[9];
#pragma unroll
    for (int j = 0; j < 9; j++) {
        dot[j] = 0.f;
        int dy = (j / 3) * 2 - 2, dx = (j % 3) * 2 - 2;
        int yy = y + dy, xx = x + dx;
        val[j] = (yy >= 0 && yy < H && xx >= 0 && xx < W);
        off[j] = yy * W + xx;
    }
    const float* qp = q + (size_t)n * KD * H * W + p;
    const float* kp = k + (size_t)n * KD * H * W;
    for (int c = 0; c < KD; c++) {
        float qa = qp[(size_t)c * H * W];
        const float* kc = kp + (size_t)c * H * W;
#pragma unroll
        for (int j = 0; j < 9; j++)
            if (val[j]) dot[j] += qa * kc[off[j]];
    }
    float m = dot[0];
#pragma unroll
    for (int j = 1; j < 9; j++) m = fmaxf(m, dot[j]);
    float s = 0.f, e[9];
#pragma unroll
    for (int j = 0; j < 9; j++) { e[j] = expf(dot[j] - m); s += e[j]; }
    float inv = 1.f / s;
    float* ap = att + ((size_t)n * H * W + p) * 9;
#pragma unroll
    for (int j = 0; j < 9; j++) ap[j] = e[j] * inv;
}

// ---------------------------------------------------------------------------
// K5: apply attention: out[n,c,y,x] = sum_j att[n,y,x,j] * v[n,c,y+dy,x+dx]
// (zero pad). grid (HW/256, C, N).
// ---------------------------------------------------------------------------
template <typename Tv, typename Tout>
__global__ void k_apply(const float* __restrict__ att, const Tv* __restrict__ v,
                        Tout* __restrict__ out, int C, int H, int W)
{
    int p = blockIdx.x * 256 + threadIdx.x;
    int c = blockIdx.y, n = blockIdx.z;
    if (p >= H * W) return;
    int y = p / W, x = p % W;
    const float* ap = att + ((size_t)n * H * W + p) * 9;
    const Tv* vp = v + ((size_t)n * C + c) * H * W;
    float s = 0.f;
#pragma unroll
    for (int j = 0; j < 9; j++) {
        int dy = (j / 3) * 2 - 2, dx = (j % 3) * 2 - 2;
        int yy = y + dy, xx = x + dx;
        if (yy >= 0 && yy < H && xx >= 0 && xx < W) s += ap[j] * ldv(vp[yy * W + xx]);
    }
    stv(&out[((size_t)n * C + c) * H * W + p], s);
}

// ---------------------------------------------------------------------------
// K6: adaptive avg pool (torch bins) from bf16 out3 [N,512,64,64].
// One wave (64 thr) per (bin, c, n). grid (s*s, C, N).
// ---------------------------------------------------------------------------
__global__ void k_apool(const bf16* __restrict__ in, float* __restrict__ out,
                        int C, int s)
{
    int bin = blockIdx.x, c = blockIdx.y, n = blockIdx.z;
    int bi = bin / s, bj = bin % s;
    int h0 = (bi * 64) / s, h1 = ((bi + 1) * 64 + s - 1) / s;
    int w0 = (bj * 64) / s, w1 = ((bj + 1) * 64 + s - 1) / s;
    int nh = h1 - h0, nw = w1 - w0, tot = nh * nw;
    const bf16* p = in + ((size_t)n * C + c) * 4096;
    float sum = 0.f;
    for (int i = threadIdx.x; i < tot; i += 64) {
        int yy = h0 + i / nw, xx = w0 + i % nw;
        sum += b2f(p[yy * 64 + xx]);
    }
#pragma unroll
    for (int o = 32; o > 0; o >>= 1) sum += __shfl_down(sum, o);
    if (threadIdx.x == 0) out[((size_t)n * C + c) * s * s + bin] = sum / tot;
}

// ---------------------------------------------------------------------------
// K7: precompute M[n][seg][j][g][co] = sum_c w[co, 512+seg*512+c, j] *
// fpool_seg[n, c, g]. Exact factorization of "3x3 conv over bilinear-
// upsampled pooled planes". grid (2 co-tiles, 50 flattened (seg,g)).
// ---------------------------------------------------------------------------
__global__ __launch_bounds__(256) void k_precm(
    const float* __restrict__ fpool, const float* __restrict__ wgt,
    float* __restrict__ M)
{
    int gflat = blockIdx.y;
    int seg, g, s;
    if (gflat < 1)       { seg = 0; g = gflat;      s = 1; }
    else if (gflat < 5)  { seg = 1; g = gflat - 1;  s = 2; }
    else if (gflat < 14) { seg = 2; g = gflat - 5;  s = 3; }
    else                 { seg = 3; g = gflat - 14; s = 6; }
    const int pofs[4] = {0, 2048, 10240, 28672};
    const int moff[4] = {0, 4608, 23040, 64512};
    int t = threadIdx.x;
    int co = blockIdx.x * 256 + t;
    int cbase = 512 + seg * 512;
    __shared__ float fsm[4][512];
    for (int i = t; i < 4 * 512; i += 256) {
        int nn = i >> 9, c = i & 511;
        fsm[nn][c] = fpool[pofs[seg] + ((size_t)(nn * 512 + c)) * s * s + g];
    }
    __syncthreads();
    float acc[4][9];
#pragma unroll
    for (int nn = 0; nn < 4; nn++)
#pragma unroll
        for (int j = 0; j < 9; j++) acc[nn][j] = 0.f;
    const float* wp = wgt + ((size_t)co * 2560 + cbase) * 9;
    for (int c = 0; c < 512; c++) {
        float w9[9];
#pragma unroll
        for (int j = 0; j < 9; j++) w9[j] = wp[c * 9 + j];
#pragma unroll
        for (int nn = 0; nn < 4; nn++) {
            float f = fsm[nn][c];
#pragma unroll
            for (int j = 0; j < 9; j++) acc[nn][j] += f * w9[j];
        }
    }
    int G = s * s;
#pragma unroll
    for (int nn = 0; nn < 4; nn++)
#pragma unroll
        for (int j = 0; j < 9; j++)
            M[(size_t)nn * 230400 + moff[seg] + ((size_t)j * G + g) * 512 + co]
                = acc[nn][j];
}

// ---------------------------------------------------------------------------
// K7b: materialize the correction field corr[n,co,y,x] (bf16) from M.
// block 256: x = t&63, 16 co per thread. grid (64 y, 8 co-tiles, N).
// ---------------------------------------------------------------------------
__global__ __launch_bounds__(256) void k_corr(
    const float* __restrict__ M, bf16* __restrict__ corr)
{
    int y = blockIdx.x;
    int n = blockIdx.z;
    int t = threadIdx.x;
    int x = t & 63;
    int co0 = blockIdx.y * 64 + (t >> 6) * 16;
    const float* Mn = M + (size_t)n * 230400;
    const int sarr[3] = {2, 3, 6};
    const int moff[3] = {4608, 23040, 64512};
    float acc[16];
#pragma unroll
    for (int i = 0; i < 16; i++) acc[i] = 0.f;
#pragma unroll
    for (int j = 0; j < 9; j++) {
        int yy = y + j / 3 - 1, xx = x + j % 3 - 1;
        if (yy < 0 || yy > 63 || xx < 0 || xx > 63) continue;
        const float* mp = Mn + (size_t)j * 512 + co0;
#pragma unroll
        for (int i = 0; i < 16; i++) acc[i] += mp[i];
#pragma unroll
        for (int sg = 0; sg < 3; sg++) {
            int s = sarr[sg];
            int G = s * s;
            float scl = (float)(s - 1) * (1.f / 63.f);
            float ty = yy * scl, tx = xx * scl;
            int y0 = (int)ty, x0 = (int)tx;
            int y1 = min(y0 + 1, s - 1), x1 = min(x0 + 1, s - 1);
            float wy = ty - (float)y0, wx = tx - (float)x0;
            float cw00 = (1.f - wy) * (1.f - wx), cw01 = (1.f - wy) * wx;
            float cw10 = wy * (1.f - wx),          cw11 = wy * wx;
            const float* Ms = Mn + moff[sg];
            const float* m00 = Ms + ((size_t)j * G + y0 * s + x0) * 512 + co0;
            const float* m01 = Ms + ((size_t)j * G + y0 * s + x1) * 512 + co0;
            const float* m10 = Ms + ((size_t)j * G + y1 * s + x0) * 512 + co0;
            const float* m11 = Ms + ((size_t)j * G + y1 * s + x1) * 512 + co0;
#pragma unroll
            for (int i = 0; i < 16; i++)
                acc[i] += cw00 * m00[i] + cw01 * m01[i]
                        + cw10 * m10[i] + cw11 * m11[i];
        }
    }
#pragma unroll
    for (int i = 0; i < 16; i++)
        corr[(((size_t)n * 512 + co0 + i) * 64 + y) * 64 + x] = __float2bfloat16(acc[i]);
}

// ---------------------------------------------------------------------------
// K8: 3x3 conv + BN + ReLU over 64x64, fp32 register-blocked. Only the 512
// REAL channels (out3, bf16) go through the direct conv; virtual channels
// arrive via precomputed corr plane added in epilogue.
// Weights staged [cl][j][co] -> 2 x float4 broadcast reads per (cl,j).
// block 256; tile 32 rows x 64 cols; thread: 8 rows x 8 co accumulators.
// grid (2 rowtiles, 64 cotiles, N). bf16 output (internal).
// ---------------------------------------------------------------------------
#define CCAT 2560
__global__ __launch_bounds__(256) void k_pcw(
    const bf16* __restrict__ out3, const float* __restrict__ wgt,
    const float* __restrict__ sc, const float* __restrict__ bi,
    const bf16* __restrict__ corr, bf16* __restrict__ out)
{
    __shared__ float tile[2][34 * 66];
    __shared__ float wsm[2 * 9 * 8];   // [cl][j][co] (144 < 256 threads: ok)
    int t = threadIdx.x;
    int col = t & 63, rowg = t >> 6;
    int rbase = blockIdx.x * 32;
    int co0 = blockIdx.y * 8;
    int n = blockIdx.z;
    float acc[8][8];  // [co][row]
#pragma unroll
    for (int a = 0; a < 8; a++)
#pragma unroll
        for (int b = 0; b < 8; b++) acc[a][b] = 0.f;
    const bf16* inn = out3 + (size_t)n * 512 * 4096;
    for (int ci0 = 0; ci0 < 512; ci0 += 2) {
        __syncthreads();
        for (int i = t; i < 2 * 2244; i += 256) {
            int cl = i / 2244, r = i % 2244;
            int yy = r / 66 - 1 + rbase, xx = r % 66 - 1;
            float v = 0.f;
            if (yy >= 0 && yy < 64 && xx >= 0 && xx < 64)
                v = b2f(inn[(size_t)(ci0 + cl) * 4096 + yy * 64 + xx]);
            tile[cl][r] = v;
        }
        if (t < 144) {  // t -> (cl, j, co) with layout ((cl*9)+j)*8+co
            int cl = t / 72, r = t % 72, j = r >> 3, co = r & 7;
            wsm[t] = wgt[((size_t)(co0 + co) * CCAT + ci0 + cl) * 9 + j];
        }
        __syncthreads();
#pragma unroll
        for (int cl = 0; cl < 2; cl++) {
#pragma unroll
            for (int j = 0; j < 9; j++) {
                int dy = j / 3, dx = j % 3;
                float v[8];
#pragma unroll
                for (int rr = 0; rr < 8; rr++)
                    v[rr] = tile[cl][(rowg * 8 + rr + dy) * 66 + col + dx];
                const float4* wp = reinterpret_cast<const float4*>(&wsm[(cl * 9 + j) * 8]);
                float4 wa = wp[0], wb = wp[1];
                float w8[8] = {wa.x, wa.y, wa.z, wa.w, wb.x, wb.y, wb.z, wb.w};
#pragma unroll
                for (int co = 0; co < 8; co++)
#pragma unroll
                    for (int rr = 0; rr < 8; rr++) acc[co][rr] += w8[co] * v[rr];
            }
        }
    }
    // virtual-channel contribution: one coalesced bf16 load per output
    const bf16* cp = corr + ((size_t)n * 512 + co0) * 4096;
#pragma unroll
    for (int co = 0; co < 8; co++) {
#pragma unroll
        for (int rr = 0; rr < 8; rr++) {
            int y = rbase + rowg * 8 + rr;
            acc[co][rr] += b2f(cp[(size_t)co * 4096 + y * 64 + col]);
        }
    }
#pragma unroll
    for (int co = 0; co < 8; co++) {
        float s = sc[co0 + co], b = bi[co0 + co];
#pragma unroll
        for (int rr = 0; rr < 8; rr++) {
            int y = rbase + rowg * 8 + rr;
            float r = fmaxf(acc[co][rr] * s + b, 0.f);
            out[(((size_t)n * 512 + co0 + co) * 64 + y) * 64 + col] = __float2bfloat16(r);
        }
    }
}

// ---------------------------------------------------------------------------
// K9: final 1x1 conv 512->19 + bias, f32 out. grid (16, N), block 256.
// ---------------------------------------------------------------------------
__global__ void k_final(const bf16* __restrict__ in, const float* __restrict__ wgt,
                        const float* __restrict__ bi, float* __restrict__ out)
{
    int p = blockIdx.x * 256 + threadIdx.x;
    int n = blockIdx.y;
    float acc[19];
#pragma unroll
    for (int j = 0; j < 19; j++) acc[j] = bi[j];
    const bf16* ip = in + (size_t)n * 512 * 4096 + p;
    for (int ci = 0; ci < 512; ci++) {
        float v = b2f(ip[(size_t)ci * 4096]);
#pragma unroll
        for (int j = 0; j < 19; j++) acc[j] += wgt[j * 512 + ci] * v;
    }
#pragma unroll
    for (int j = 0; j < 19; j++)
        out[((size_t)n * 19 + j) * 4096 + p] = acc[j];
}

// ---------------------------------------------------------------------------
extern "C" void kernel_launch(void* const* d_in, const int* in_sizes, int n_in,
                              void* d_out, int out_size, void* d_ws, size_t ws_size,
                              hipStream_t stream)
{
    // ALL inputs are float32 (per the reference's setup_inputs dtypes).
    const float* c2   = (const float*)d_in[1];
    const float* c3   = (const float*)d_in[2];
    const float* c4   = (const float*)d_in[3];
    const float* w5   = (const float*)d_in[4];
    const float* s5   = (const float*)d_in[5];
    const float* b5   = (const float*)d_in[6];
    const float* r4w  = (const float*)d_in[7];
    const float* r4s  = (const float*)d_in[8];
    const float* r4b  = (const float*)d_in[9];
    const float* r4w2 = (const float*)d_in[10];
    const float* r4s2 = (const float*)d_in[11];
    const float* r4b2 = (const float*)d_in[12];
    const float* r3w  = (const float*)d_in[13];
    const float* r3s  = (const float*)d_in[14];
    const float* r3b  = (const float*)d_in[15];
    const float* r3w2 = (const float*)d_in[16];
    const float* r3s2 = (const float*)d_in[17];
    const float* r3b2 = (const float*)d_in[18];
    const float* pw[4] = { (const float*)d_in[19], (const float*)d_in[22],
                           (const float*)d_in[25], (const float*)d_in[28] };
    const float* ps[4] = { (const float*)d_in[20], (const float*)d_in[23],
                           (const float*)d_in[26], (const float*)d_in[29] };
    const float* pb[4] = { (const float*)d_in[21], (const float*)d_in[24],
                           (const float*)d_in[27], (const float*)d_in[30] };
    const float* pcw  = (const float*)d_in[31];
    const float* pcs  = (const float*)d_in[32];
    const float* pcb  = (const float*)d_in[33];
    const float* w6   = (const float*)d_in[34];
    const float* b6   = (const float*)d_in[35];
    float* outp = (float*)d_out;

    // --- workspace arena, peak 58,490,880 B (55.8 MiB). Live ranges:
    // R0 [0,15728640): out5[T1..T4], q4/k4[T2..T3], att4[T3..T5],
    //                  out5r[T4..T5]; then q3/k3[T6..T7], att3[T7..T9];
    //                  then Mbuf [T10.5..T11) at 0 and out_pc [T11..T12)
    //                  at 3686400
    // R1: out4 f32 [T5..T8]; tail of out_pc overlaps (out4 dead) ok
    // R2: [24117248): pbuf f32 33.5MB [T1 only]; out4r bf16 [T8..T9];
    //                 corr bf16 [T10.6..T11] (all disjoint in time)
    // R3: out3 bf16 [T9..T11]
    // R4: pooled/fpool f32 [T10..T10.5]
    char* ws = (char*)d_ws;
    float* out5   = (float*)(ws + 0);          // 2,097,152
    float* q4     = (float*)(ws + 2097152);    // 2,097,152
    float* k4     = (float*)(ws + 4194304);    // 2,097,152
    float* att4   = (float*)(ws + 6291456);    //   147,456
    float* out5r  = (float*)(ws + 6438912);    // 8,388,608 (ends 14,827,520)
    float* q3     = (float*)(ws + 0);          // 4,194,304 (R0 reuse)
    float* k3     = (float*)(ws + 4194304);    // 4,194,304
    float* att3   = (float*)(ws + 8388608);    //   589,824
    float* Mbuf   = (float*)(ws + 0);          // 3,686,400 (R0 reuse, T10.5+)
    bf16*  out_pc = (bf16*)(ws + 3686400);     // 16,777,216 (ends 20,463,616)
    float* out4   = (float*)(ws + 15728640);   // 8,388,608
    float* pbuf   = (float*)(ws + 24117248);   // 33,554,432 (T1 only)
    bf16*  out4r  = (bf16*)(ws + 24117248);    // 16,777,216 (T8..T9)
    bf16*  corr   = (bf16*)(ws + 24117248);    // alias, disjoint in time
    bf16*  out3   = (bf16*)(ws + 40894464);    // 16,777,216
    float* pooled = (float*)(ws + 57671680);   //   409,600
    float* fpool  = (float*)(ws + 58081280);   //   409,600 (ends 58,490,880)

    // T1: out5 = relu(bn(conv3x3(c4, w5)))           [4,512,16,16]
    k_conv3x3_ks<<<dim3(64, 16), 256, 0, stream>>>(c4, w5, pbuf);
    k_red16<<<2048, 256, 0, stream>>>(pbuf, s5, b5, out5);
    // T2: q4 = bn(conv1x1(c3)); k4 = bn(conv1x1(resize(c4,32))) fused
    k_conv1x1<float><<<dim3(4, 8, 4), 256, 0, stream>>>(c3, r4w, r4s, r4b, q4, 1024, 128, 1024, 0);
    k_conv1x1_up<16><<<dim3(4, 8, 4), 256, 0, stream>>>(c4, r4w2, r4s2, r4b2, k4, 2048, 128);
    // T3: att4 = softmax(q4 . unfold(k4))            [4,32,32,9]
    k_attn<<<dim3(4, 4), 256, 0, stream>>>(q4, k4, att4, 128, 32, 32);
    // T4: out5r = resize(out5, 32x32)
    k_resize<float, float><<<8192, 256, 0, stream>>>(out5, out5r, 4, 512, 16, 16, 32, 32);
    // T5: out4 = att4 * unfold(out5r)                [4,512,32,32]
    k_apply<float, float><<<dim3(4, 512, 4), 256, 0, stream>>>(att4, out5r, out4, 512, 32, 32);
    // T6: q3 = bn(conv1x1(c2)); k3 = bn(conv1x1(resize(c3,64))) fused
    k_conv1x1<float><<<dim3(16, 4, 4), 256, 0, stream>>>(c2, r3w, r3s, r3b, q3, 512, 64, 4096, 0);
    k_conv1x1_up<32><<<dim3(16, 4, 4), 256, 0, stream>>>(c3, r3w2, r3s2, r3b2, k3, 1024, 64);
    // T7: att3                                        [4,64,64,9]
    k_attn<<<dim3(16, 4), 256, 0, stream>>>(q3, k3, att3, 64, 64, 64);
    // T8: out4r = resize(out4, 64x64) -> bf16
    k_resize<float, bf16><<<32768, 256, 0, stream>>>(out4, out4r, 4, 512, 32, 32, 64, 64);
    // T9: out3 = att3 * unfold(out4r) -> bf16        [4,512,64,64]
    k_apply<bf16, bf16><<<dim3(16, 512, 4), 256, 0, stream>>>(att3, out4r, out3, 512, 64, 64);
    // T10: PSP pools + 1x1 conv+bn+relu -> fpool (tiny)
    const int scales[4] = {1, 2, 3, 6};
    const int poff[4] = {0, 2048, 10240, 28672};  // f32 elem offsets
    for (int i = 0; i < 4; i++) {
        int s = scales[i];
        k_apool<<<dim3(s * s, 512, 4), 64, 0, stream>>>(out3, pooled + poff[i], 512, s);
        k_conv1x1<float><<<dim3(1, 32, 4), 256, 0, stream>>>(pooled + poff[i], pw[i], ps[i], pb[i],
                                                             fpool + poff[i], 512, 512, s * s, 1);
    }
    // T10.5: M[n,seg,j,g,co] = sum_c pcw[co,512+seg*512+c,j] * fpool[n,c,g]
    k_precm<<<dim3(2, 50), 256, 0, stream>>>(fpool, pcw, Mbuf);
    // T10.6: corr[n,co,y,x] = per-pixel bilinear combination of M (bf16)
    k_corr<<<dim3(64, 8, 4), 256, 0, stream>>>(Mbuf, corr);
    // T11: out_pc = relu(bn(conv3x3(real 512 ch) + corr)) [4,512,64,64] bf16
    k_pcw<<<dim3(2, 64, 4), 256, 0, stream>>>(out3, pcw, pcs, pcb, corr, out_pc);
    // T12: out = conv1x1(out_pc, w6) + b6 -> f32     [4,19,64,64]
    k_final<<<dim3(16, 4), 256, 0, stream>>>(out_pc, w6, b6, outp);
}

// Round 8
// 5499.712 us; speedup vs baseline: 7.4923x; 1.1099x over previous
//
#include <hip/hip_runtime.h>
#include <hip/hip_bf16.h>
#include <cstddef>

typedef __hip_bfloat16 bf16;

__device__ __forceinline__ float b2f(bf16 x) { return __bfloat162float(x); }
__device__ __forceinline__ float ldv(float x) { return x; }
__device__ __forceinline__ float ldv(bf16 x) { return __bfloat162float(x); }
__device__ __forceinline__ void stv(float* p, float v) { *p = v; }
__device__ __forceinline__ void stv(bf16* p, float v) { *p = __float2bfloat16(v); }

// ---------------------------------------------------------------------------
// K1: 3x3 conv pad1 on 16x16 planes, 2048ci -> 512co, K-SPLIT 16.
// grid (64 co-tiles, 16 k). BN+ReLU in k_red16.  (round-4 code, PASSING)
// ---------------------------------------------------------------------------
__global__ __launch_bounds__(256, 2) void k_conv3x3_ks(
    const float* __restrict__ in,   // [4,2048,16,16]
    const float* __restrict__ wgt,  // [512,2048,3,3]
    float* __restrict__ pbuf)       // [16,4,512,256]
{
    __shared__ float tile[16 * 432];   // [nn*4+cc][18 rows * 24 stride]
    __shared__ float wsm[4 * 9 * 8];   // [cc][j][co]
    int t = threadIdx.x;
    int x = t & 15, y = t >> 4;
    int co0 = blockIdx.x * 8;
    int k = blockIdx.y;
    int ci_beg = k * 128;
    float acc[8][4];  // [co][nn]
#pragma unroll
    for (int a = 0; a < 8; a++)
#pragma unroll
        for (int b = 0; b < 4; b++) acc[a][b] = 0.f;
    for (int ci0 = ci_beg; ci0 < ci_beg + 128; ci0 += 4) {
        __syncthreads();
        for (int i = t; i < 16 * 324; i += 256) {
            int pl = i / 324, r = i % 324;
            int nn = pl >> 2, cc = pl & 3;
            int yy = r / 18 - 1, xx = r % 18 - 1;
            float v = 0.f;
            if (yy >= 0 && yy < 16 && xx >= 0 && xx < 16)
                v = in[(((size_t)nn * 2048 + ci0 + cc) << 8) + (yy << 4) + xx];
            tile[pl * 432 + (r / 18) * 24 + (r % 18)] = v;
        }
        for (int i = t; i < 288; i += 256) {  // strided: 288 > blockDim
            int cc = i / 72;
            int r = i % 72, j = r >> 3, co = r & 7;
            wsm[i] = wgt[((size_t)(co0 + co) * 2048 + ci0 + cc) * 9 + j];
        }
        __syncthreads();
#pragma unroll
        for (int cc = 0; cc < 4; cc++) {
#pragma unroll
            for (int j = 0; j < 9; j++) {
                int dy = j / 3, dx = j % 3;
                float vv[4];
#pragma unroll
                for (int nn = 0; nn < 4; nn++)
                    vv[nn] = tile[(nn * 4 + cc) * 432 + (y + dy) * 24 + (x + dx)];
                const float4* wp = reinterpret_cast<const float4*>(&wsm[(cc * 9 + j) * 8]);
                float4 wa = wp[0], wb = wp[1];
                float w8[8] = {wa.x, wa.y, wa.z, wa.w, wb.x, wb.y, wb.z, wb.w};
#pragma unroll
                for (int co = 0; co < 8; co++)
#pragma unroll
                    for (int nn = 0; nn < 4; nn++)
                        acc[co][nn] += w8[co] * vv[nn];
            }
        }
    }
#pragma unroll
    for (int co = 0; co < 8; co++)
#pragma unroll
        for (int nn = 0; nn < 4; nn++)
            pbuf[(((size_t)k * 4 + nn) * 512 + co0 + co) * 256 + t] = acc[co][nn];
}

// ---------------------------------------------------------------------------
// K1b: reduce 16 partials + BN + ReLU -> out5 [4,512,16,16].
// ---------------------------------------------------------------------------
__global__ void k_red16(const float* __restrict__ pbuf,
                        const float* __restrict__ sc, const float* __restrict__ bi,
                        float* __restrict__ out)
{
    int idx = blockIdx.x * 256 + threadIdx.x;
    int p = idx & 255;
    int co = (idx >> 8) & 511;
    int n = idx >> 17;
    float s = 0.f;
#pragma unroll
    for (int k = 0; k < 16; k++)
        s += pbuf[(((size_t)k * 4 + n) * 512 + co) * 256 + p];
    out[idx] = fmaxf(s * sc[co] + bi[co], 0.f);
}

// ---------------------------------------------------------------------------
// K2: bilinear resize, align_corners=True. thread per output element.
// ---------------------------------------------------------------------------
template <typename Tin, typename Tout>
__global__ void k_resize(const Tin* __restrict__ in, Tout* __restrict__ out,
                         int N, int C, int h, int w, int H, int W)
{
    size_t idx = (size_t)blockIdx.x * blockDim.x + threadIdx.x;
    size_t total = (size_t)N * C * H * W;
    if (idx >= total) return;
    int X = idx % W; size_t r = idx / W;
    int Y = r % H; r /= H;
    int c = r % C; int n = (int)(r / C);
    float sy = (H > 1) ? (float)(h - 1) / (float)(H - 1) : 0.f;
    float sx = (W > 1) ? (float)(w - 1) / (float)(W - 1) : 0.f;
    float ty = Y * sy, tx = X * sx;
    int y0 = (int)floorf(ty), x0 = (int)floorf(tx);
    int y1 = min(y0 + 1, h - 1), x1 = min(x0 + 1, w - 1);
    float wy = ty - y0, wx = tx - x0;
    const Tin* p = in + ((size_t)n * C + c) * h * w;
    float v00 = ldv(p[y0 * w + x0]), v01 = ldv(p[y0 * w + x1]);
    float v10 = ldv(p[y1 * w + x0]), v11 = ldv(p[y1 * w + x1]);
    float v = (v00 * (1.f - wy) + v10 * wy) * (1.f - wx)
            + (v01 * (1.f - wy) + v11 * wy) * wx;
    stv(&out[idx], v);
}

// ---------------------------------------------------------------------------
// K3: 1x1 conv + BN (+opt ReLU), f32 weights. block 256 pixels, co-tile 16.
// grid (ceil(HW/256), CO/16, N).  (round-4 code, PASSING)
// ---------------------------------------------------------------------------
template <typename Tin>
__global__ void k_conv1x1(const Tin* __restrict__ in, const float* __restrict__ wgt,
                          const float* __restrict__ sc, const float* __restrict__ bi,
                          float* __restrict__ out, int CI, int CO, int HW, int relu)
{
    int p = blockIdx.x * 256 + threadIdx.x;
    int co0 = blockIdx.y * 16;
    int n = blockIdx.z;
    if (p >= HW) return;
    const Tin* ip = in + (size_t)n * CI * HW + p;
    float acc[16];
#pragma unroll
    for (int i = 0; i < 16; i++) acc[i] = 0.f;
    for (int ci = 0; ci < CI; ci++) {
        float v = ldv(ip[(size_t)ci * HW]);
#pragma unroll
        for (int co = 0; co < 16; co++)
            acc[co] += wgt[(size_t)(co0 + co) * CI + ci] * v;
    }
#pragma unroll
    for (int co = 0; co < 16; co++) {
        float r = acc[co] * sc[co0 + co] + bi[co0 + co];
        if (relu) r = fmaxf(r, 0.f);
        out[((size_t)n * CO + co0 + co) * HW + p] = r;
    }
}

// ---------------------------------------------------------------------------
// K3b: fused bilinear-2x-upsample + 1x1 conv + BN. (round-4 code, PASSING)
// ---------------------------------------------------------------------------
template <int SH>
__global__ void k_conv1x1_up(const float* __restrict__ in, const float* __restrict__ wgt,
                             const float* __restrict__ sc, const float* __restrict__ bi,
                             float* __restrict__ out, int CI, int CO)
{
    const int OH = 2 * SH, HW = OH * OH, sHW = SH * SH;
    int p = blockIdx.x * 256 + threadIdx.x;
    int co0 = blockIdx.y * 16;
    int n = blockIdx.z;
    if (p >= HW) return;
    int Y = p / OH, X = p % OH;
    float s = (float)(SH - 1) / (float)(OH - 1);
    float ty = Y * s, tx = X * s;
    int y0 = (int)floorf(ty), x0 = (int)floorf(tx);
    int y1 = min(y0 + 1, SH - 1), x1 = min(x0 + 1, SH - 1);
    float wy = ty - y0, wx = tx - x0;
    float w00 = (1.f - wy) * (1.f - wx), w01 = (1.f - wy) * wx;
    float w10 = wy * (1.f - wx),         w11 = wy * wx;
    int o00 = y0 * SH + x0, o01 = y0 * SH + x1;
    int o10 = y1 * SH + x0, o11 = y1 * SH + x1;
    const float* ip = in + (size_t)n * CI * sHW;
    float acc[16];
#pragma unroll
    for (int i = 0; i < 16; i++) acc[i] = 0.f;
    for (int ci = 0; ci < CI; ci++) {
        const float* pp = ip + (size_t)ci * sHW;
        float v = w00 * pp[o00] + w01 * pp[o01] + w10 * pp[o10] + w11 * pp[o11];
#pragma unroll
        for (int co = 0; co < 16; co++)
            acc[co] += wgt[(size_t)(co0 + co) * CI + ci] * v;
    }
#pragma unroll
    for (int co = 0; co < 16; co++)
        out[((size_t)n * CO + co0 + co) * HW + p] =
            acc[co] * sc[co0 + co] + bi[co0 + co];
}

// ---------------------------------------------------------------------------
// K4: attention logits + softmax. q,k: [N,KD,H,W] f32 -> att [N,H,W,9].
// ---------------------------------------------------------------------------
__global__ void k_attn(const float* __restrict__ q, const float* __restrict__ k,
                       float* __restrict__ att, int KD, int H, int W)
{
    int p = blockIdx.x * 256 + threadIdx.x;
    int n = blockIdx.y;
    if (p >= H * W) return;
    int y = p / W, x = p % W;
    float dot[9];
    bool val[9];
    int off[9];
#pragma unroll
    for (int j = 0; j < 9; j++) {
        dot[j] = 0.f;
        int dy = (j / 3) * 2 - 2, dx = (j % 3) * 2 - 2;
        int yy = y + dy, xx = x + dx;
        val[j] = (yy >= 0 && yy < H && xx >= 0 && xx < W);
        off[j] = yy * W + xx;
    }
    const float* qp = q + (size_t)n * KD * H * W + p;
    const float* kp = k + (size_t)n * KD * H * W;
    for (int c = 0; c < KD; c++) {
        float qa = qp[(size_t)c * H * W];
        const float* kc = kp + (size_t)c * H * W;
#pragma unroll
        for (int j = 0; j < 9; j++)
            if (val[j]) dot[j] += qa * kc[off[j]];
    }
    float m = dot[0];
#pragma unroll
    for (int j = 1; j < 9; j++) m = fmaxf(m, dot[j]);
    float s = 0.f, e[9];
#pragma unroll
    for (int j = 0; j < 9; j++) { e[j] = expf(dot[j] - m); s += e[j]; }
    float inv = 1.f / s;
    float* ap = att + ((size_t)n * H * W + p) * 9;
#pragma unroll
    for (int j = 0; j < 9; j++) ap[j] = e[j] * inv;
}

// ---------------------------------------------------------------------------
// K5: apply attention. grid (HW/256, C, N).
// ---------------------------------------------------------------------------
template <typename Tv, typename Tout>
__global__ void k_apply(const float* __restrict__ att, const Tv* __restrict__ v,
                        Tout* __restrict__ out, int C, int H, int W)
{
    int p = blockIdx.x * 256 + threadIdx.x;
    int c = blockIdx.y, n = blockIdx.z;
    if (p >= H * W) return;
    int y = p / W, x = p % W;
    const float* ap = att + ((size_t)n * H * W + p) * 9;
    const Tv* vp = v + ((size_t)n * C + c) * H * W;
    float s = 0.f;
#pragma unroll
    for (int j = 0; j < 9; j++) {
        int dy = (j / 3) * 2 - 2, dx = (j % 3) * 2 - 2;
        int yy = y + dy, xx = x + dx;
        if (yy >= 0 && yy < H && xx >= 0 && xx < W) s += ap[j] * ldv(vp[yy * W + xx]);
    }
    stv(&out[((size_t)n * C + c) * H * W + p], s);
}

// ---------------------------------------------------------------------------
// K6: adaptive avg pool (torch bins) from bf16 out3 [N,512,64,64].
// ---------------------------------------------------------------------------
__global__ void k_apool(const bf16* __restrict__ in, float* __restrict__ out,
                        int C, int s)
{
    int bin = blockIdx.x, c = blockIdx.y, n = blockIdx.z;
    int bi = bin / s, bj = bin % s;
    int h0 = (bi * 64) / s, h1 = ((bi + 1) * 64 + s - 1) / s;
    int w0 = (bj * 64) / s, w1 = ((bj + 1) * 64 + s - 1) / s;
    int nh = h1 - h0, nw = w1 - w0, tot = nh * nw;
    const bf16* p = in + ((size_t)n * C + c) * 4096;
    float sum = 0.f;
    for (int i = threadIdx.x; i < tot; i += 64) {
        int yy = h0 + i / nw, xx = w0 + i % nw;
        sum += b2f(p[yy * 64 + xx]);
    }
#pragma unroll
    for (int o = 32; o > 0; o >>= 1) sum += __shfl_down(sum, o);
    if (threadIdx.x == 0) out[((size_t)n * C + c) * s * s + bin] = sum / tot;
}

// ---------------------------------------------------------------------------
// K7: precompute M[n][seg][j][g][co] (exact PSP-conv factorization).
// ---------------------------------------------------------------------------
__global__ __launch_bounds__(256) void k_precm(
    const float* __restrict__ fpool, const float* __restrict__ wgt,
    float* __restrict__ M)
{
    int gflat = blockIdx.y;
    int seg, g, s;
    if (gflat < 1)       { seg = 0; g = gflat;      s = 1; }
    else if (gflat < 5)  { seg = 1; g = gflat - 1;  s = 2; }
    else if (gflat < 14) { seg = 2; g = gflat - 5;  s = 3; }
    else                 { seg = 3; g = gflat - 14; s = 6; }
    const int pofs[4] = {0, 2048, 10240, 28672};
    const int moff[4] = {0, 4608, 23040, 64512};
    int t = threadIdx.x;
    int co = blockIdx.x * 256 + t;
    int cbase = 512 + seg * 512;
    __shared__ float fsm[4][512];
    for (int i = t; i < 4 * 512; i += 256) {
        int nn = i >> 9, c = i & 511;
        fsm[nn][c] = fpool[pofs[seg] + ((size_t)(nn * 512 + c)) * s * s + g];
    }
    __syncthreads();
    float acc[4][9];
#pragma unroll
    for (int nn = 0; nn < 4; nn++)
#pragma unroll
        for (int j = 0; j < 9; j++) acc[nn][j] = 0.f;
    const float* wp = wgt + ((size_t)co * 2560 + cbase) * 9;
    for (int c = 0; c < 512; c++) {
        float w9[9];
#pragma unroll
        for (int j = 0; j < 9; j++) w9[j] = wp[c * 9 + j];
#pragma unroll
        for (int nn = 0; nn < 4; nn++) {
            float f = fsm[nn][c];
#pragma unroll
            for (int j = 0; j < 9; j++) acc[nn][j] += f * w9[j];
        }
    }
    int G = s * s;
#pragma unroll
    for (int nn = 0; nn < 4; nn++)
#pragma unroll
        for (int j = 0; j < 9; j++)
            M[(size_t)nn * 230400 + moff[seg] + ((size_t)j * G + g) * 512 + co]
                = acc[nn][j];
}

// ---------------------------------------------------------------------------
// K7b: materialize correction field corr[n,co,y,x] (bf16) from M.
// ---------------------------------------------------------------------------
__global__ __launch_bounds__(256) void k_corr(
    const float* __restrict__ M, bf16* __restrict__ corr)
{
    int y = blockIdx.x;
    int n = blockIdx.z;
    int t = threadIdx.x;
    int x = t & 63;
    int co0 = blockIdx.y * 64 + (t >> 6) * 16;
    const float* Mn = M + (size_t)n * 230400;
    const int sarr[3] = {2, 3, 6};
    const int moff[3] = {4608, 23040, 64512};
    float acc[16];
#pragma unroll
    for (int i = 0; i < 16; i++) acc[i] = 0.f;
#pragma unroll
    for (int j = 0; j < 9; j++) {
        int yy = y + j / 3 - 1, xx = x + j % 3 - 1;
        if (yy < 0 || yy > 63 || xx < 0 || xx > 63) continue;
        const float* mp = Mn + (size_t)j * 512 + co0;
#pragma unroll
        for (int i = 0; i < 16; i++) acc[i] += mp[i];
#pragma unroll
        for (int sg = 0; sg < 3; sg++) {
            int s = sarr[sg];
            int G = s * s;
            float scl = (float)(s - 1) * (1.f / 63.f);
            float ty = yy * scl, tx = xx * scl;
            int y0 = (int)ty, x0 = (int)tx;
            int y1 = min(y0 + 1, s - 1), x1 = min(x0 + 1, s - 1);
            float wy = ty - (float)y0, wx = tx - (float)x0;
            float cw00 = (1.f - wy) * (1.f - wx), cw01 = (1.f - wy) * wx;
            float cw10 = wy * (1.f - wx),          cw11 = wy * wx;
            const float* Ms = Mn + moff[sg];
            const float* m00 = Ms + ((size_t)j * G + y0 * s + x0) * 512 + co0;
            const float* m01 = Ms + ((size_t)j * G + y0 * s + x1) * 512 + co0;
            const float* m10 = Ms + ((size_t)j * G + y1 * s + x0) * 512 + co0;
            const float* m11 = Ms + ((size_t)j * G + y1 * s + x1) * 512 + co0;
#pragma unroll
            for (int i = 0; i < 16; i++)
                acc[i] += cw00 * m00[i] + cw01 * m01[i]
                        + cw10 * m10[i] + cw11 * m11[i];
        }
    }
#pragma unroll
    for (int i = 0; i < 16; i++)
        corr[(((size_t)n * 512 + co0 + i) * 64 + y) * 64 + x] = __float2bfloat16(acc[i]);
}

// ---------------------------------------------------------------------------
// K8: 3x3 conv + BN + ReLU over 64x64, 512 real ch + corr plane.
// BISECT: ONLY change vs round-4 PASS is 16-row tiles -> grid (4,64,4)
// (4 blocks/CU, was 2). Staging is round-4's scalar b2f, zero-filled.
// Tile stride 72, cols 3..68 = x=-1..64.
// block 256: col=t&63, rowg=t>>6; thread: 4 rows x 8 co.
// ---------------------------------------------------------------------------
#define CCAT 2560
__global__ __launch_bounds__(256) void k_pcw(
    const bf16* __restrict__ out3, const float* __restrict__ wgt,
    const float* __restrict__ sc, const float* __restrict__ bi,
    const bf16* __restrict__ corr, bf16* __restrict__ out)
{
    __shared__ float tile[2][18 * 72];
    __shared__ float wsm[2 * 9 * 8];   // [cl][j][co]
    int t = threadIdx.x;
    int col = t & 63, rowg = t >> 6;
    int rbase = blockIdx.x * 16;
    int co0 = blockIdx.y * 8;
    int n = blockIdx.z;
    float acc[8][4];  // [co][row]
#pragma unroll
    for (int a = 0; a < 8; a++)
#pragma unroll
        for (int b = 0; b < 4; b++) acc[a][b] = 0.f;
    const bf16* inn = out3 + (size_t)n * 512 * 4096;
    for (int ci0 = 0; ci0 < 512; ci0 += 2) {
        __syncthreads();
        for (int i = t; i < 2 * 1188; i += 256) {
            int cl = i / 1188, r = i % 1188;
            int rr = r / 66, cc = r % 66;
            int yy = rbase - 1 + rr, xx = cc - 1;
            float v = 0.f;
            if (yy >= 0 && yy < 64 && xx >= 0 && xx < 64)
                v = b2f(inn[(size_t)(ci0 + cl) * 4096 + yy * 64 + xx]);
            tile[cl][rr * 72 + 3 + cc] = v;
        }
        if (t < 144) {  // (cl, j, co), layout ((cl*9)+j)*8+co
            int cl = t / 72, r = t % 72, j = r >> 3, co = r & 7;
            wsm[t] = wgt[((size_t)(co0 + co) * CCAT + ci0 + cl) * 9 + j];
        }
        __syncthreads();
#pragma unroll
        for (int cl = 0; cl < 2; cl++) {
#pragma unroll
            for (int j = 0; j < 9; j++) {
                int dy = j / 3, dx = j % 3;
                float v[4];
#pragma unroll
                for (int rr = 0; rr < 4; rr++)
                    v[rr] = tile[cl][(rowg * 4 + rr + dy) * 72 + 3 + col + dx];
                const float4* wp = reinterpret_cast<const float4*>(&wsm[(cl * 9 + j) * 8]);
                float4 wa = wp[0], wb = wp[1];
                float w8[8] = {wa.x, wa.y, wa.z, wa.w, wb.x, wb.y, wb.z, wb.w};
#pragma unroll
                for (int co = 0; co < 8; co++)
#pragma unroll
                    for (int rr = 0; rr < 4; rr++) acc[co][rr] += w8[co] * v[rr];
            }
        }
    }
    const bf16* cp = corr + ((size_t)n * 512 + co0) * 4096;
#pragma unroll
    for (int co = 0; co < 8; co++) {
#pragma unroll
        for (int rr = 0; rr < 4; rr++) {
            int y = rbase + rowg * 4 + rr;
            acc[co][rr] += b2f(cp[(size_t)co * 4096 + y * 64 + col]);
        }
    }
#pragma unroll
    for (int co = 0; co < 8; co++) {
        float s = sc[co0 + co], b = bi[co0 + co];
#pragma unroll
        for (int rr = 0; rr < 4; rr++) {
            int y = rbase + rowg * 4 + rr;
            float r = fmaxf(acc[co][rr] * s + b, 0.f);
            out[(((size_t)n * 512 + co0 + co) * 64 + y) * 64 + col] = __float2bfloat16(r);
        }
    }
}

// ---------------------------------------------------------------------------
// K9: final 1x1 conv 512->19 + bias, f32 out. grid (16, N), block 256.
// ---------------------------------------------------------------------------
__global__ void k_final(const bf16* __restrict__ in, const float* __restrict__ wgt,
                        const float* __restrict__ bi, float* __restrict__ out)
{
    int p = blockIdx.x * 256 + threadIdx.x;
    int n = blockIdx.y;
    float acc[19];
#pragma unroll
    for (int j = 0; j < 19; j++) acc[j] = bi[j];
    const bf16* ip = in + (size_t)n * 512 * 4096 + p;
    for (int ci = 0; ci < 512; ci++) {
        float v = b2f(ip[(size_t)ci * 4096]);
#pragma unroll
        for (int j = 0; j < 19; j++) acc[j] += wgt[j * 512 + ci] * v;
    }
#pragma unroll
    for (int j = 0; j < 19; j++)
        out[((size_t)n * 19 + j) * 4096 + p] = acc[j];
}

// ---------------------------------------------------------------------------
extern "C" void kernel_launch(void* const* d_in, const int* in_sizes, int n_in,
                              void* d_out, int out_size, void* d_ws, size_t ws_size,
                              hipStream_t stream)
{
    const float* c2   = (const float*)d_in[1];
    const float* c3   = (const float*)d_in[2];
    const float* c4   = (const float*)d_in[3];
    const float* w5   = (const float*)d_in[4];
    const float* s5   = (const float*)d_in[5];
    const float* b5   = (const float*)d_in[6];
    const float* r4w  = (const float*)d_in[7];
    const float* r4s  = (const float*)d_in[8];
    const float* r4b  = (const float*)d_in[9];
    const float* r4w2 = (const float*)d_in[10];
    const float* r4s2 = (const float*)d_in[11];
    const float* r4b2 = (const float*)d_in[12];
    const float* r3w  = (const float*)d_in[13];
    const float* r3s  = (const float*)d_in[14];
    const float* r3b  = (const float*)d_in[15];
    const float* r3w2 = (const float*)d_in[16];
    const float* r3s2 = (const float*)d_in[17];
    const float* r3b2 = (const float*)d_in[18];
    const float* pw[4] = { (const float*)d_in[19], (const float*)d_in[22],
                           (const float*)d_in[25], (const float*)d_in[28] };
    const float* ps[4] = { (const float*)d_in[20], (const float*)d_in[23],
                           (const float*)d_in[26], (const float*)d_in[29] };
    const float* pb[4] = { (const float*)d_in[21], (const float*)d_in[24],
                           (const float*)d_in[27], (const float*)d_in[30] };
    const float* pcw  = (const float*)d_in[31];
    const float* pcs  = (const float*)d_in[32];
    const float* pcb  = (const float*)d_in[33];
    const float* w6   = (const float*)d_in[34];
    const float* b6   = (const float*)d_in[35];
    float* outp = (float*)d_out;

    // --- workspace arena: EXACT round-4 layout (PASSING). ---
    char* ws = (char*)d_ws;
    float* out5   = (float*)(ws + 0);          // 2,097,152
    float* q4     = (float*)(ws + 2097152);    // 2,097,152
    float* k4     = (float*)(ws + 4194304);    // 2,097,152
    float* att4   = (float*)(ws + 6291456);    //   147,456
    float* out5r  = (float*)(ws + 6438912);    // 8,388,608
    float* q3     = (float*)(ws + 0);          // 4,194,304 (R0 reuse)
    float* k3     = (float*)(ws + 4194304);    // 4,194,304
    float* att3   = (float*)(ws + 8388608);    //   589,824
    float* Mbuf   = (float*)(ws + 0);          // 3,686,400 (T10.5+)
    bf16*  out_pc = (bf16*)(ws + 3686400);     // 16,777,216 (T11+)
    float* out4   = (float*)(ws + 15728640);   // 8,388,608
    float* pbuf   = (float*)(ws + 24117248);   // 33,554,432 (T1 only)
    bf16*  out4r  = (bf16*)(ws + 24117248);    // 16,777,216 (T8..T9)
    bf16*  corr   = (bf16*)(ws + 24117248);    // alias, disjoint in time
    bf16*  out3   = (bf16*)(ws + 40894464);    // 16,777,216
    float* pooled = (float*)(ws + 57671680);   //   409,600
    float* fpool  = (float*)(ws + 58081280);   //   409,600 (ends 58,490,880)

    // T1: out5 = relu(bn(conv3x3(c4, w5)))           [4,512,16,16]
    k_conv3x3_ks<<<dim3(64, 16), 256, 0, stream>>>(c4, w5, pbuf);
    k_red16<<<2048, 256, 0, stream>>>(pbuf, s5, b5, out5);
    // T2: q4 = bn(conv1x1(c3)); k4 = bn(conv1x1(resize(c4,32))) fused
    k_conv1x1<float><<<dim3(4, 8, 4), 256, 0, stream>>>(c3, r4w, r4s, r4b, q4, 1024, 128, 1024, 0);
    k_conv1x1_up<16><<<dim3(4, 8, 4), 256, 0, stream>>>(c4, r4w2, r4s2, r4b2, k4, 2048, 128);
    // T3: att4 = softmax(q4 . unfold(k4))            [4,32,32,9]
    k_attn<<<dim3(4, 4), 256, 0, stream>>>(q4, k4, att4, 128, 32, 32);
    // T4: out5r = resize(out5, 32x32)
    k_resize<float, float><<<8192, 256, 0, stream>>>(out5, out5r, 4, 512, 16, 16, 32, 32);
    // T5: out4 = att4 * unfold(out5r)                [4,512,32,32]
    k_apply<float, float><<<dim3(4, 512, 4), 256, 0, stream>>>(att4, out5r, out4, 512, 32, 32);
    // T6: q3 = bn(conv1x1(c2)); k3 = bn(conv1x1(resize(c3,64))) fused
    k_conv1x1<float><<<dim3(16, 4, 4), 256, 0, stream>>>(c2, r3w, r3s, r3b, q3, 512, 64, 4096, 0);
    k_conv1x1_up<32><<<dim3(16, 4, 4), 256, 0, stream>>>(c3, r3w2, r3s2, r3b2, k3, 1024, 64);
    // T7: att3                                        [4,64,64,9]
    k_attn<<<dim3(16, 4), 256, 0, stream>>>(q3, k3, att3, 64, 64, 64);
    // T8: out4r = resize(out4, 64x64) -> bf16
    k_resize<float, bf16><<<32768, 256, 0, stream>>>(out4, out4r, 4, 512, 32, 32, 64, 64);
    // T9: out3 = att3 * unfold(out4r) -> bf16        [4,512,64,64]
    k_apply<bf16, bf16><<<dim3(16, 512, 4), 256, 0, stream>>>(att3, out4r, out3, 512, 64, 64);
    // T10: PSP pools + 1x1 conv+bn+relu -> fpool (tiny)  (round-4 path)
    const int scales[4] = {1, 2, 3, 6};
    const int poff[4] = {0, 2048, 10240, 28672};  // f32 elem offsets
    for (int i = 0; i < 4; i++) {
        int s = scales[i];
        k_apool<<<dim3(s * s, 512, 4), 64, 0, stream>>>(out3, pooled + poff[i], 512, s);
        k_conv1x1<float><<<dim3(1, 32, 4), 256, 0, stream>>>(pooled + poff[i], pw[i], ps[i], pb[i],
                                                             fpool + poff[i], 512, 512, s * s, 1);
    }
    // T10.5: M factorization
    k_precm<<<dim3(2, 50), 256, 0, stream>>>(fpool, pcw, Mbuf);
    // T10.6: corr field
    k_corr<<<dim3(64, 8, 4), 256, 0, stream>>>(Mbuf, corr);
    // T11: out_pc = relu(bn(conv3x3(real 512 ch) + corr)) [4,512,64,64] bf16
    k_pcw<<<dim3(4, 64, 4), 256, 0, stream>>>(out3, pcw, pcs, pcb, corr, out_pc);
    // T12: out = conv1x1(out_pc, w6) + b6 -> f32     [4,19,64,64]
    k_final<<<dim3(16, 4), 256, 0, stream>>>(out_pc, w6, b6, outp);
}